// Round 2
// baseline (1499.106 us; speedup 1.0000x reference)
//
#include <hip/hip_runtime.h>
#include <math.h>

#define N 4096

static constexpr float F_EPS     = 0.1f;
static constexpr float F_IEPS    = 10.0f;                  // 1/EPS
static constexpr float F_LOGZ    = -0.46470802658470073f;  // ln(2*pi*0.1)
static constexpr float F_EPSLOGZ = -0.046470802658470075f; // EPS*LOGZ
static constexpr float F_ATOL    = 1e-4f;
static constexpr float F_RTOL    = 1e-4f;
static constexpr float F_THRESH  = 100.0f;
static constexpr int   NITER     = 200;
static constexpr int   GB        = 512;   // blocks for heavy kernels (8 rows/block)
static constexpr int   BT        = 256;

// ---------- wave helpers (deterministic fixed-order reductions) ----------
__device__ __forceinline__ float wsum(float x) {
#pragma unroll
  for (int o = 32; o; o >>= 1) x += __shfl_xor(x, o, 64);
  return x;
}
__device__ __forceinline__ float wmax(float x) {
#pragma unroll
  for (int o = 32; o; o >>= 1) x = fmaxf(x, __shfl_xor(x, o, 64));
  return x;
}
__device__ __forceinline__ float cost_ij(float2 xi, float x2i, float2 yj, float y2j) {
  const float dot = xi.x * yj.x + xi.y * yj.y;
  return 0.5f * fmaxf(x2i + y2j - 2.0f * dot, 0.0f);
}

// ---------- init: precompute per-point constants, reset state/flags ----------
__global__ void init_kernel(const float* __restrict__ xw, const float2* __restrict__ xs,
                            const float* __restrict__ yw, const float2* __restrict__ ys,
                            float* u, float* v, float* av, float* bv,
                            float* x2, float* y2, float* ci, float* cj,
                            float* lxw, float* lyw, float* ywn, int* flags) {
  __shared__ float red[256];
  const int tid = threadIdx.x;
  float m = 0.f;
  for (int i = tid; i < N; i += 256) {
    u[i] = 1.f; v[i] = 1.f; av[i] = 0.f; bv[i] = 0.f;
    const float2 a = xs[i]; const float xx = a.x * a.x + a.y * a.y;
    const float2 b = ys[i]; const float yy = b.x * b.x + b.y * b.y;
    x2[i] = xx; y2[i] = yy;
    ci[i] = -F_IEPS * (0.5f * xx);            // a=0
    cj[i] = -F_IEPS * (0.5f * yy) - F_LOGZ;   // b=0, LOGZ folded here once
    lxw[i] = logf(xw[i]);
    lyw[i] = logf(yw[i]);
    m = fmaxf(m, fabsf(yw[i]));
  }
  red[tid] = m; __syncthreads();
  for (int s2 = 128; s2; s2 >>= 1) { if (tid < s2) red[tid] = fmaxf(red[tid], red[tid + s2]); __syncthreads(); }
  if (tid == 0) { ywn[0] = red[0]; flags[0] = 0; flags[1] = 0; }
}

// ---------- ub: v = yw/s (each block builds full v in LDS), then u = xw/(K v) ----------
// K_ij = exp(ci[i] + cj[j] + 10*dot(x_i,y_j)) * xw_i * yw_j  (on the fly)
__global__ void __launch_bounds__(BT) ub_kernel(
    const float* __restrict__ xw, const float* __restrict__ yw,
    const float2* __restrict__ xs, const float2* __restrict__ ys,
    const float* __restrict__ ci, const float* __restrict__ cj,
    const float* __restrict__ s,
    float* __restrict__ u, float* __restrict__ v,
    float* __restrict__ bu, float* __restrict__ bvmax,
    const int* __restrict__ flags) {
  if (flags[0]) return;   // converged earlier: freeze state
  __shared__ float ysx[N], ysy[N], cjl[N], wvl[N];   // 64 KiB
  const int tid = threadIdx.x, bid = blockIdx.x;
  const int lane = tid & 63, wib = tid >> 6;

  float mv = 0.f;
  for (int k = tid; k < N; k += BT) {
    const float yk = yw[k];
    const float vv = yk / s[k];
    const float2 yj = ys[k];
    ysx[k] = yj.x; ysy[k] = yj.y; cjl[k] = cj[k]; wvl[k] = yk * vv;
    mv = fmaxf(mv, fabsf(vv));
  }
  __syncthreads();
  if (tid < 8) { const int idx = bid * 8 + tid; v[idx] = yw[idx] / s[idx]; }
  const float wmv_ = wmax(mv);
  if (bid == 0 && lane == 0) bvmax[wib] = wmv_;   // 4 waves of block 0 cover all k

  // two rows per wave
  const int r0 = bid * 8 + wib * 2;
  const float2 x0 = xs[r0], x1 = xs[r0 + 1];
  const float ci0 = ci[r0], ci1 = ci[r0 + 1];
  float acc0 = 0.f, acc1 = 0.f;
#pragma unroll 4
  for (int t = 0; t < 64; ++t) {
    const int j = (t << 6) + lane;
    const float yx = ysx[j], yy = ysy[j], cc = cjl[j], wv = wvl[j];
    const float d0 = fmaf(x0.x, yx, x0.y * yy);
    const float d1 = fmaf(x1.x, yx, x1.y * yy);
    acc0 = fmaf(__expf(fmaf(F_IEPS, d0, ci0 + cc)), wv, acc0);
    acc1 = fmaf(__expf(fmaf(F_IEPS, d1, ci1 + cc)), wv, acc1);
  }
  acc0 = wsum(acc0); acc1 = wsum(acc1);
  if (lane == 0) {
    const float xw0 = xw[r0], xw1 = xw[r0 + 1];
    const float u0 = xw0 / (acc0 * xw0);   // (Kv)_r = xw_r * acc
    const float u1 = xw1 / (acc1 * xw1);
    u[r0] = u0; u[r0 + 1] = u1;
    bu[bid * 4 + wib] = fmaxf(fabsf(u0), fabsf(u1));
  }
}

// ---------- kt: s = K^T u  (+ err in mode 1) ----------
// mode 0: prelude (always runs, no err); mode 1: main loop (done-gated, err);
// mode 2: post-stab refresh (stab-gated, no err)
__global__ void __launch_bounds__(BT) kt_kernel(
    const float* __restrict__ xw, const float* __restrict__ yw,
    const float2* __restrict__ xs, const float2* __restrict__ ys,
    const float* __restrict__ ci, const float* __restrict__ cj,
    const float* __restrict__ u, const float* __restrict__ v,
    float* __restrict__ s, float* __restrict__ berr,
    const int* __restrict__ flags, int mode) {
  if (mode == 1 && flags[0]) return;
  if (mode == 2 && (flags[0] || !flags[1])) return;
  __shared__ float xsx[N], xsy[N], cil[N], wul[N];   // 64 KiB
  const int tid = threadIdx.x, bid = blockIdx.x;
  const int lane = tid & 63, wib = tid >> 6;

  for (int k = tid; k < N; k += BT) {
    const float2 p = xs[k];
    xsx[k] = p.x; xsy[k] = p.y; cil[k] = ci[k]; wul[k] = xw[k] * u[k];
  }
  __syncthreads();

  const int c0 = bid * 8 + wib * 2, c1 = c0 + 1;
  const float2 yA = ys[c0], yB = ys[c1];
  const float cjA = cj[c0], cjB = cj[c1];
  float a0 = 0.f, a1 = 0.f;
#pragma unroll 4
  for (int t = 0; t < 64; ++t) {
    const int i = (t << 6) + lane;
    const float px = xsx[i], py = xsy[i], cc = cil[i], wu = wul[i];
    const float dA = fmaf(px, yA.x, py * yA.y);
    const float dB = fmaf(px, yB.x, py * yB.y);
    a0 = fmaf(__expf(fmaf(F_IEPS, dA, cc + cjA)), wu, a0);
    a1 = fmaf(__expf(fmaf(F_IEPS, dB, cc + cjB)), wu, a1);
  }
  a0 = wsum(a0); a1 = wsum(a1);
  if (lane == 0) {
    const float ywA = yw[c0], ywB = yw[c1];
    const float sA = ywA * a0, sB = ywB * a1;   // (K^T u)_c = yw_c * acc
    s[c0] = sA; s[c1] = sB;
    if (mode == 1) {
      const float e0 = fabsf(v[c0] * sA - ywA);
      const float e1 = fabsf(v[c1] * sB - ywB);
      berr[bid * 4 + wib] = fmaxf(e0, e1);
    }
  }
}

// ---------- decide: reduce partial maxima, set done/stab, absorb if stab ----------
__global__ void decide_kernel(int* flags,
                              const float* __restrict__ bu, const float* __restrict__ berr,
                              const float* __restrict__ bvmax, const float* __restrict__ ywn_p,
                              float* u, float* v, float* av, float* bv,
                              const float* __restrict__ x2, const float* __restrict__ y2,
                              float* ci, float* cj) {
  if (flags[0]) return;
  __shared__ float re[256], ru[256];
  const int tid = threadIdx.x;
  float e = 0.f, mu = 0.f;
  for (int k = tid; k < 2048; k += 256) { e = fmaxf(e, berr[k]); mu = fmaxf(mu, bu[k]); }
  re[tid] = e; ru[tid] = mu; __syncthreads();
  for (int s2 = 128; s2; s2 >>= 1) {
    if (tid < s2) { re[tid] = fmaxf(re[tid], re[tid + s2]); ru[tid] = fmaxf(ru[tid], ru[tid + s2]); }
    __syncthreads();
  }
  e = re[0]; mu = ru[0];
  const float mv = fmaxf(fmaxf(bvmax[0], bvmax[1]), fmaxf(bvmax[2], bvmax[3]));
  const bool done = (e < F_ATOL) || (e / ywn_p[0] < F_RTOL);
  const bool stab = (!done) && (fmaxf(mu, mv) > F_THRESH);
  if (tid == 0) { flags[0] = done ? 1 : 0; flags[1] = stab ? 1 : 0; }
  if (stab) {
    for (int i = tid; i < N; i += 256) {
      const float a2 = av[i] - F_EPS * logf(u[i]);
      const float b2 = bv[i] - F_EPS * logf(v[i]);
      av[i] = a2; bv[i] = b2;
      u[i] = 1.f; v[i] = 1.f;
      ci[i] = -F_IEPS * (0.5f * x2[i] + a2);
      cj[i] = -F_IEPS * (0.5f * y2[i] + b2) - F_LOGZ;
    }
  }
}

// ---------- objective tail ----------
__global__ void fg_kernel(const float* u, const float* v, const float* av, const float* bv,
                          float* f, float* g) {
  const int i = blockIdx.x * blockDim.x + threadIdx.x;
  if (i < N) {
    f[i] = -F_EPS * logf(u[i]) + av[i];
    g[i] = -F_EPS * logf(v[i]) + bv[i];
  }
}

__global__ void __launch_bounds__(256) fcts_kernel(const float2* __restrict__ xs,
                                                   const float2* __restrict__ ys,
                                                   const float* __restrict__ x2,
                                                   const float* __restrict__ y2,
                                                   const float* __restrict__ g,
                                                   const float* __restrict__ lyw,
                                                   float* __restrict__ fc) {
  const int lane = threadIdx.x & 63;
  const int wg = (blockIdx.x * blockDim.x + threadIdx.x) >> 6;
  const int nw = (gridDim.x * blockDim.x) >> 6;
  for (int i = wg; i < N; i += nw) {
    const float2 xi = xs[i];
    const float x2i = x2[i];
    float m = -3.4e38f;
    for (int j = lane; j < N; j += 64) {
      const float z = (-cost_ij(xi, x2i, ys[j], y2[j]) - g[j]) * F_IEPS + lyw[j];
      m = fmaxf(m, z);
    }
    m = wmax(m);
    float ss = 0.f;
    for (int j = lane; j < N; j += 64) {
      const float z = (-cost_ij(xi, x2i, ys[j], y2[j]) - g[j]) * F_IEPS + lyw[j];
      ss += __expf(z - m);
    }
    ss = wsum(ss);
    if (lane == 0) fc[i] = F_EPS * (logf(ss) + m) - F_EPSLOGZ;
  }
}

__global__ void __launch_bounds__(256) gcts_kernel(const float2* __restrict__ xs,
                                                   const float2* __restrict__ ys,
                                                   const float* __restrict__ x2,
                                                   const float* __restrict__ y2,
                                                   const float* __restrict__ f,
                                                   const float* __restrict__ lxw,
                                                   float* __restrict__ gc) {
  const int lane = threadIdx.x & 63;
  const int wg = (blockIdx.x * blockDim.x + threadIdx.x) >> 6;
  const int nw = (gridDim.x * blockDim.x) >> 6;
  for (int j = wg; j < N; j += nw) {
    const float2 yj = ys[j];
    const float y2j = y2[j];
    float m = -3.4e38f;
    for (int i = lane; i < N; i += 64) {
      const float z = (-cost_ij(xs[i], x2[i], yj, y2j) - f[i]) * F_IEPS + lxw[i];
      m = fmaxf(m, z);
    }
    m = wmax(m);
    float ss = 0.f;
    for (int i = lane; i < N; i += 64) {
      const float z = (-cost_ij(xs[i], x2[i], yj, y2j) - f[i]) * F_IEPS + lxw[i];
      ss += __expf(z - m);
    }
    ss = wsum(ss);
    if (lane == 0) gc[j] = F_EPS * (logf(ss) + m) - F_EPSLOGZ;
  }
}

__global__ void __launch_bounds__(256) plan_kernel(const float2* __restrict__ xs,
                                                   const float2* __restrict__ ys,
                                                   const float* __restrict__ x2,
                                                   const float* __restrict__ y2,
                                                   const float* __restrict__ xw,
                                                   const float* __restrict__ yw,
                                                   const float* __restrict__ fc,
                                                   const float* __restrict__ gc,
                                                   float* __restrict__ part) {
  __shared__ float red[256];
  const int tid = threadIdx.x;
  const int rpb = N / gridDim.x;
  const int r0 = blockIdx.x * rpb;
  float acc = 0.f;
  for (int i = r0; i < r0 + rpb; ++i) {
    const float2 xi = xs[i];
    const float x2i = x2[i], fi = fc[i], xwi = xw[i];
    for (int j = tid; j < N; j += 256) {
      const float Cij = cost_ij(xi, x2i, ys[j], y2[j]);
      acc += __expf(-(Cij + fi + gc[j]) * F_IEPS - F_LOGZ) * xwi * yw[j];
    }
  }
  red[tid] = acc; __syncthreads();
  for (int s2 = 128; s2; s2 >>= 1) { if (tid < s2) red[tid] += red[tid + s2]; __syncthreads(); }
  if (tid == 0) part[blockIdx.x] = red[0];
}

__global__ void final_kernel(const float* fc, const float* gc,
                             const float* xw, const float* yw,
                             const float* part, int npart, float* out) {
  __shared__ float r1[256], r2[256], r3[256];
  const int tid = threadIdx.x;
  float a1 = 0.f, a2 = 0.f, a3 = 0.f;
  for (int i = tid; i < N; i += 256) { a1 += fc[i] * xw[i]; a2 += gc[i] * yw[i]; }
  for (int i = tid; i < npart; i += 256) a3 += part[i];
  r1[tid] = a1; r2[tid] = a2; r3[tid] = a3; __syncthreads();
  for (int s2 = 128; s2; s2 >>= 1) {
    if (tid < s2) { r1[tid] += r1[tid + s2]; r2[tid] += r2[tid + s2]; r3[tid] += r3[tid + s2]; }
    __syncthreads();
  }
  if (tid == 0) out[0] = -r1[0] - r2[0] - F_EPS * r3[0];
}

extern "C" void kernel_launch(void* const* d_in, const int* in_sizes, int n_in,
                              void* d_out, int out_size, void* d_ws, size_t ws_size,
                              hipStream_t stream) {
  const float*  xw  = (const float*)d_in[0];
  const float2* xs2 = (const float2*)d_in[1];
  const float*  yw  = (const float*)d_in[2];
  const float2* ys2 = (const float2*)d_in[3];
  float* out = (float*)d_out;

  float* w = (float*)d_ws;
  float *u    = w,           *v    = w + 4096,   *av  = w + 8192,  *bv  = w + 12288,
        *s    = w + 16384,   *x2   = w + 20480,  *y2  = w + 24576,
        *ci   = w + 28672,   *cj   = w + 32768,  *lxw = w + 36864, *lyw = w + 40960,
        *f    = w + 45056,   *g    = w + 49152,  *fc  = w + 53248, *gc  = w + 57344,
        *part = w + 61440,   *bu   = w + 61952,  *berr = w + 64000,
        *bvmax = w + 66048,  *ywn  = w + 66112;
  int* flags = (int*)(w + 66116);

  init_kernel<<<1, 256, 0, stream>>>(xw, xs2, yw, ys2, u, v, av, bv, x2, y2, ci, cj,
                                     lxw, lyw, ywn, flags);
  // prelude: s = K^T @ 1
  kt_kernel<<<GB, BT, 0, stream>>>(xw, yw, xs2, ys2, ci, cj, u, v, s, berr, flags, 0);

  for (int it = 0; it < NITER; ++it) {
    ub_kernel<<<GB, BT, 0, stream>>>(xw, yw, xs2, ys2, ci, cj, s, u, v, bu, bvmax, flags);
    kt_kernel<<<GB, BT, 0, stream>>>(xw, yw, xs2, ys2, ci, cj, u, v, s, berr, flags, 1);
    decide_kernel<<<1, 256, 0, stream>>>(flags, bu, berr, bvmax, ywn, u, v, av, bv, x2, y2, ci, cj);
    kt_kernel<<<GB, BT, 0, stream>>>(xw, yw, xs2, ys2, ci, cj, u, v, s, berr, flags, 2);
  }

  fg_kernel<<<16, 256, 0, stream>>>(u, v, av, bv, f, g);
  fcts_kernel<<<GB, 256, 0, stream>>>(xs2, ys2, x2, y2, g, lyw, fc);
  gcts_kernel<<<GB, 256, 0, stream>>>(xs2, ys2, x2, y2, f, lxw, gc);
  plan_kernel<<<GB, 256, 0, stream>>>(xs2, ys2, x2, y2, xw, yw, fc, gc, part);
  final_kernel<<<1, 256, 0, stream>>>(fc, gc, xw, yw, part, GB, out);
}

// Round 3
// 804.707 us; speedup vs baseline: 1.8629x; 1.8629x over previous
//
#include <hip/hip_runtime.h>
#include <math.h>

#define N 4096

static constexpr float F_EPS     = 0.1f;
static constexpr float F_IEPS    = 10.0f;                  // 1/EPS
static constexpr float F_LOGZ    = -0.46470802658470073f;  // ln(2*pi*0.1)
static constexpr float F_EPSLOGZ = -0.046470802658470075f; // EPS*LOGZ
static constexpr float F_ATOL    = 1e-4f;
static constexpr float F_RTOL    = 1e-4f;
static constexpr float F_THRESH  = 100.0f;
static constexpr int   NITER     = 200;
static constexpr int   NBH       = 256;   // heavy-kernel blocks (1/CU)
static constexpr int   BT        = 256;   // threads/block (4 waves)
static constexpr int   CPB       = 16;    // columns|rows per block
static constexpr int   CPW       = 4;     // per wave

// ---------- wave helpers (deterministic fixed-order reductions) ----------
__device__ __forceinline__ float wsum(float x) {
#pragma unroll
  for (int o = 32; o; o >>= 1) x += __shfl_xor(x, o, 64);
  return x;
}
__device__ __forceinline__ float wmax(float x) {
#pragma unroll
  for (int o = 32; o; o >>= 1) x = fmaxf(x, __shfl_xor(x, o, 64));
  return x;
}
__device__ __forceinline__ float aload(const float* p) {
  return __hip_atomic_load(p, __ATOMIC_RELAXED, __HIP_MEMORY_SCOPE_AGENT);
}

// ---------- init ----------
__global__ void init_kernel(const float* __restrict__ xw, const float2* __restrict__ xs,
                            const float* __restrict__ yw, const float2* __restrict__ ys,
                            float* u, float* v, float* av, float* bv,
                            float* x2, float* y2, float* ci, float* cj,
                            float* ywn, int* flags, unsigned* cntC, unsigned* cntR) {
  __shared__ float red[256];
  const int tid = threadIdx.x;
  float m = 0.f;
  for (int i = tid; i < N; i += 256) {
    u[i] = 1.f; v[i] = 1.f; av[i] = 0.f; bv[i] = 0.f;
    const float2 a = xs[i]; const float xx = a.x * a.x + a.y * a.y;
    const float2 b = ys[i]; const float yy = b.x * b.x + b.y * b.y;
    x2[i] = xx; y2[i] = yy;
    ci[i] = -F_IEPS * (0.5f * xx);            // -IEPS*(x2/2 + av), av=0
    cj[i] = -F_IEPS * (0.5f * yy) - F_LOGZ;   // -IEPS*(y2/2 + bv) - LOGZ
    m = fmaxf(m, fabsf(yw[i]));
  }
  red[tid] = m; __syncthreads();
  for (int s2 = 128; s2; s2 >>= 1) { if (tid < s2) red[tid] = fmaxf(red[tid], red[tid + s2]); __syncthreads(); }
  if (tid == 0) { ywn[0] = red[0]; flags[0] = 0; cntC[0] = 0u; cntR[0] = 0u; }
}

// ---------- col pass: s = K^T u ; (mode1) err partials + done decision in tail block ----------
__global__ void __launch_bounds__(BT) colpass_kernel(
    const float* __restrict__ xw, const float* __restrict__ yw,
    const float2* __restrict__ xs, const float2* __restrict__ ys,
    const float* __restrict__ ci, const float* __restrict__ cj,
    const float* __restrict__ u, const float* __restrict__ v,
    float* __restrict__ s, float* __restrict__ berr,
    const float* __restrict__ ywn, int* flags, unsigned* cnt, int mode) {
  if (mode && flags[0]) return;
  __shared__ __align__(16) float sx[N], sy[N], cu[N];   // 48 KiB
  __shared__ float ew[4], rt[BT];
  __shared__ int tailflag;
  const int tid = threadIdx.x, bid = blockIdx.x;
  const int lane = tid & 63, wib = tid >> 6;

  for (int k = tid; k < N; k += BT) {
    const float2 p = xs[k];
    sx[k] = p.x; sy[k] = p.y;
    cu[k] = ci[k] + logf(xw[k] * u[k]);   // weight folded into exp-arg (xw*u > 0)
  }
  __syncthreads();

  const int c0 = bid * CPB + wib * CPW;
  const float2 y0 = ys[c0], y1 = ys[c0 + 1], y2v = ys[c0 + 2], y3 = ys[c0 + 3];
  float a0 = 0.f, a1 = 0.f, a2 = 0.f, a3 = 0.f;
#pragma unroll 4
  for (int t = 0; t < 64; ++t) {
    const int i = (t << 6) + lane;
    const float xx = sx[i], xy = sy[i], w = cu[i];
    a0 += __expf(fmaf(F_IEPS, fmaf(xx, y0.x, xy * y0.y), w));
    a1 += __expf(fmaf(F_IEPS, fmaf(xx, y1.x, xy * y1.y), w));
    a2 += __expf(fmaf(F_IEPS, fmaf(xx, y2v.x, xy * y2v.y), w));
    a3 += __expf(fmaf(F_IEPS, fmaf(xx, y3.x, xy * y3.y), w));
  }
  a0 = wsum(a0); a1 = wsum(a1); a2 = wsum(a2); a3 = wsum(a3);

  if (lane == 0) {
    float acc[4] = {a0, a1, a2, a3};
    float e = 0.f;
#pragma unroll
    for (int q = 0; q < 4; ++q) {
      const int c = c0 + q;
      const float sc = yw[c] * __expf(cj[c]) * acc[q];   // (K^T u)_c
      s[c] = sc;
      if (mode) e = fmaxf(e, fabsf(v[c] * sc - yw[c]));
    }
    ew[wib] = e;
  }
  if (!mode) return;
  __syncthreads();
  if (tid == 0) {
    berr[bid] = fmaxf(fmaxf(ew[0], ew[1]), fmaxf(ew[2], ew[3]));
    __threadfence();
    const unsigned old = atomicAdd(cnt, 1u);
    tailflag = (old == NBH - 1) ? 1 : 0;
  }
  __syncthreads();
  if (tailflag) {
    __threadfence();
    rt[tid] = aload(&berr[tid]);   // NBH == BT
    __syncthreads();
    for (int s2 = 128; s2; s2 >>= 1) { if (tid < s2) rt[tid] = fmaxf(rt[tid], rt[tid + s2]); __syncthreads(); }
    if (tid == 0) {
      const float err = rt[0];
      if ((err < F_ATOL) || (err / ywn[0] < F_RTOL)) flags[0] = 1;
      cnt[0] = 0u;
    }
  }
}

// ---------- row pass: v = yw/s, u = xw/(K v); tail block: eager absorb if needed ----------
__global__ void __launch_bounds__(BT) rowpass_kernel(
    const float* __restrict__ xw, const float* __restrict__ yw,
    const float2* __restrict__ xs, const float2* __restrict__ ys,
    float* ci, float* cj, float* av, float* bv,
    const float* __restrict__ x2, const float* __restrict__ y2,
    float* u, float* v, const float* __restrict__ s,
    float* bu, const int* __restrict__ flags, unsigned* cnt) {
  if (flags[0]) return;
  __shared__ __align__(16) float yxs[N], yys[N], cw[N];  // 48 KiB
  __shared__ float mw[4], uw[4], rt[BT];
  __shared__ float mvs;
  __shared__ int tailflag;
  const int tid = threadIdx.x, bid = blockIdx.x;
  const int lane = tid & 63, wib = tid >> 6;

  float mv = 0.f;
  for (int k = tid; k < N; k += BT) {
    const float ywk = yw[k];
    const float vv = ywk / s[k];
    if ((k >> 4) == bid) v[k] = vv;   // owned slice of v (CPB=16)
    const float2 p = ys[k];
    yxs[k] = p.x; yys[k] = p.y;
    cw[k] = cj[k] + logf(ywk * vv);   // weight folded (yw*v > 0)
    mv = fmaxf(mv, fabsf(vv));
  }
  mv = wmax(mv);
  if (lane == 0) mw[wib] = mv;
  __syncthreads();

  const int r0 = bid * CPB + wib * CPW;
  const float2 x0 = xs[r0], x1 = xs[r0 + 1], x2v = xs[r0 + 2], x3 = xs[r0 + 3];
  float a0 = 0.f, a1 = 0.f, a2 = 0.f, a3 = 0.f;
#pragma unroll 4
  for (int t = 0; t < 64; ++t) {
    const int j = (t << 6) + lane;
    const float yx = yxs[j], yy = yys[j], w = cw[j];
    a0 += __expf(fmaf(F_IEPS, fmaf(x0.x, yx, x0.y * yy), w));
    a1 += __expf(fmaf(F_IEPS, fmaf(x1.x, yx, x1.y * yy), w));
    a2 += __expf(fmaf(F_IEPS, fmaf(x2v.x, yx, x2v.y * yy), w));
    a3 += __expf(fmaf(F_IEPS, fmaf(x3.x, yx, x3.y * yy), w));
  }
  a0 = wsum(a0); a1 = wsum(a1); a2 = wsum(a2); a3 = wsum(a3);

  if (lane == 0) {
    float acc[4] = {a0, a1, a2, a3};
    float mu = 0.f;
#pragma unroll
    for (int q = 0; q < 4; ++q) {
      const int r = r0 + q;
      const float xr = xw[r];
      const float kv = xr * __expf(ci[r]) * acc[q];   // (K v)_r
      const float ur = xr / kv;
      u[r] = ur;
      mu = fmaxf(mu, fabsf(ur));
    }
    uw[wib] = mu;
  }
  __syncthreads();
  if (tid == 0) {
    bu[bid] = fmaxf(fmaxf(uw[0], uw[1]), fmaxf(uw[2], uw[3]));
    mvs = fmaxf(fmaxf(mw[0], mw[1]), fmaxf(mw[2], mw[3]));   // global max|v| (each block saw all)
    __threadfence();
    const unsigned old = atomicAdd(cnt, 1u);
    tailflag = (old == NBH - 1) ? 1 : 0;
  }
  __syncthreads();
  if (tailflag) {
    __threadfence();
    rt[tid] = aload(&bu[tid]);
    __syncthreads();
    for (int s2 = 128; s2; s2 >>= 1) { if (tid < s2) rt[tid] = fmaxf(rt[tid], rt[tid + s2]); __syncthreads(); }
    // Eager absorption: K_new = diag(u) K diag(v) makes err/f/g invariant, so
    // absorbing without knowing `done` preserves the reference trajectory.
    if (fmaxf(rt[0], mvs) > F_THRESH) {
      for (int i = tid; i < N; i += BT) {
        const float ui = aload(&u[i]);
        const float vi = aload(&v[i]);
        const float na = av[i] - F_EPS * logf(ui);
        const float nb = bv[i] - F_EPS * logf(vi);
        av[i] = na; bv[i] = nb;
        ci[i] = -F_IEPS * (0.5f * x2[i] + na);
        cj[i] = -F_IEPS * (0.5f * y2[i] + nb) - F_LOGZ;
        u[i] = 1.f; v[i] = 1.f;
      }
    }
    if (tid == 0) cnt[0] = 0u;
  }
}

// ---------- objective tail ----------
// fc_i = EPS*( -5*x2_i + m + log sum exp(B_j + 10*dot - m) ) - EPS*LOGZ,
// B_j = -5*y2_j - 10*bv_j + log v_j + log yw_j
__global__ void __launch_bounds__(BT) fcts_kernel(
    const float* __restrict__ xw, const float* __restrict__ yw,
    const float2* __restrict__ xs, const float2* __restrict__ ys,
    const float* __restrict__ x2, const float* __restrict__ y2,
    const float* __restrict__ v, const float* __restrict__ bv,
    float* __restrict__ fc) {
  __shared__ __align__(16) float yxs[N], yys[N], B[N];
  const int tid = threadIdx.x, bid = blockIdx.x;
  const int lane = tid & 63, wib = tid >> 6;
  for (int k = tid; k < N; k += BT) {
    const float2 p = ys[k];
    yxs[k] = p.x; yys[k] = p.y;
    B[k] = fmaf(-5.f, y2[k], fmaf(-10.f, bv[k], logf(v[k]) + logf(yw[k])));
  }
  __syncthreads();
  const int r0 = bid * CPB + wib * CPW;
  const float2 x0 = xs[r0], x1 = xs[r0 + 1], x2v = xs[r0 + 2], x3 = xs[r0 + 3];
  float m0 = -3.4e38f, m1 = m0, m2 = m0, m3 = m0;
#pragma unroll 4
  for (int t = 0; t < 64; ++t) {
    const int j = (t << 6) + lane;
    const float yx = yxs[j], yy = yys[j], w = B[j];
    m0 = fmaxf(m0, fmaf(F_IEPS, fmaf(x0.x, yx, x0.y * yy), w));
    m1 = fmaxf(m1, fmaf(F_IEPS, fmaf(x1.x, yx, x1.y * yy), w));
    m2 = fmaxf(m2, fmaf(F_IEPS, fmaf(x2v.x, yx, x2v.y * yy), w));
    m3 = fmaxf(m3, fmaf(F_IEPS, fmaf(x3.x, yx, x3.y * yy), w));
  }
  m0 = wmax(m0); m1 = wmax(m1); m2 = wmax(m2); m3 = wmax(m3);
  float s0 = 0.f, s1 = 0.f, s2 = 0.f, s3 = 0.f;
#pragma unroll 4
  for (int t = 0; t < 64; ++t) {
    const int j = (t << 6) + lane;
    const float yx = yxs[j], yy = yys[j], w = B[j];
    s0 += __expf(fmaf(F_IEPS, fmaf(x0.x, yx, x0.y * yy), w) - m0);
    s1 += __expf(fmaf(F_IEPS, fmaf(x1.x, yx, x1.y * yy), w) - m1);
    s2 += __expf(fmaf(F_IEPS, fmaf(x2v.x, yx, x2v.y * yy), w) - m2);
    s3 += __expf(fmaf(F_IEPS, fmaf(x3.x, yx, x3.y * yy), w) - m3);
  }
  s0 = wsum(s0); s1 = wsum(s1); s2 = wsum(s2); s3 = wsum(s3);
  if (lane == 0) {
    const float mm[4] = {m0, m1, m2, m3}; const float ss[4] = {s0, s1, s2, s3};
#pragma unroll
    for (int q = 0; q < 4; ++q) {
      const int r = r0 + q;
      fc[r] = F_EPS * (-5.f * x2[r] + mm[q] + logf(ss[q])) - F_EPSLOGZ;
    }
  }
}

// gc_j = EPS*( -5*y2_j + m + log sum exp(Bx_i + 10*dot - m) ) - EPS*LOGZ,
// Bx_i = -5*x2_i - 10*av_i + log u_i + log xw_i
__global__ void __launch_bounds__(BT) gcts_kernel(
    const float* __restrict__ xw, const float* __restrict__ yw,
    const float2* __restrict__ xs, const float2* __restrict__ ys,
    const float* __restrict__ x2, const float* __restrict__ y2,
    const float* __restrict__ u, const float* __restrict__ av,
    float* __restrict__ gc) {
  __shared__ __align__(16) float sx[N], sy[N], B[N];
  const int tid = threadIdx.x, bid = blockIdx.x;
  const int lane = tid & 63, wib = tid >> 6;
  for (int k = tid; k < N; k += BT) {
    const float2 p = xs[k];
    sx[k] = p.x; sy[k] = p.y;
    B[k] = fmaf(-5.f, x2[k], fmaf(-10.f, av[k], logf(u[k]) + logf(xw[k])));
  }
  __syncthreads();
  const int c0 = bid * CPB + wib * CPW;
  const float2 y0 = ys[c0], y1 = ys[c0 + 1], y2v = ys[c0 + 2], y3 = ys[c0 + 3];
  float m0 = -3.4e38f, m1 = m0, m2 = m0, m3 = m0;
#pragma unroll 4
  for (int t = 0; t < 64; ++t) {
    const int i = (t << 6) + lane;
    const float xx = sx[i], xy = sy[i], w = B[i];
    m0 = fmaxf(m0, fmaf(F_IEPS, fmaf(xx, y0.x, xy * y0.y), w));
    m1 = fmaxf(m1, fmaf(F_IEPS, fmaf(xx, y1.x, xy * y1.y), w));
    m2 = fmaxf(m2, fmaf(F_IEPS, fmaf(xx, y2v.x, xy * y2v.y), w));
    m3 = fmaxf(m3, fmaf(F_IEPS, fmaf(xx, y3.x, xy * y3.y), w));
  }
  m0 = wmax(m0); m1 = wmax(m1); m2 = wmax(m2); m3 = wmax(m3);
  float s0 = 0.f, s1 = 0.f, s2 = 0.f, s3 = 0.f;
#pragma unroll 4
  for (int t = 0; t < 64; ++t) {
    const int i = (t << 6) + lane;
    const float xx = sx[i], xy = sy[i], w = B[i];
    s0 += __expf(fmaf(F_IEPS, fmaf(xx, y0.x, xy * y0.y), w) - m0);
    s1 += __expf(fmaf(F_IEPS, fmaf(xx, y1.x, xy * y1.y), w) - m1);
    s2 += __expf(fmaf(F_IEPS, fmaf(xx, y2v.x, xy * y2v.y), w) - m2);
    s3 += __expf(fmaf(F_IEPS, fmaf(xx, y3.x, xy * y3.y), w) - m3);
  }
  s0 = wsum(s0); s1 = wsum(s1); s2 = wsum(s2); s3 = wsum(s3);
  if (lane == 0) {
    const float mm[4] = {m0, m1, m2, m3}; const float ss[4] = {s0, s1, s2, s3};
#pragma unroll
    for (int q = 0; q < 4; ++q) {
      const int c = c0 + q;
      gc[c] = F_EPS * (-5.f * y2[c] + mm[q] + logf(ss[q])) - F_EPSLOGZ;
    }
  }
}

// plan partial sums: sum_ij exp(Pi_i + Pj_j + 10*dot), Pi = -5*x2-10*fc+log xw,
// Pj = -5*y2-10*gc+log yw - LOGZ
__global__ void __launch_bounds__(BT) plan_kernel(
    const float* __restrict__ xw, const float* __restrict__ yw,
    const float2* __restrict__ xs, const float2* __restrict__ ys,
    const float* __restrict__ x2, const float* __restrict__ y2,
    const float* __restrict__ fc, const float* __restrict__ gc,
    float* __restrict__ part) {
  __shared__ __align__(16) float yxs[N], yys[N], P[N];
  __shared__ float red[4];
  const int tid = threadIdx.x, bid = blockIdx.x;
  const int lane = tid & 63, wib = tid >> 6;
  for (int k = tid; k < N; k += BT) {
    const float2 p = ys[k];
    yxs[k] = p.x; yys[k] = p.y;
    P[k] = fmaf(-5.f, y2[k], fmaf(-10.f, gc[k], logf(yw[k]))) - F_LOGZ;
  }
  __syncthreads();
  const int r0 = bid * CPB + wib * CPW;
  const float2 x0 = xs[r0], x1 = xs[r0 + 1], x2v = xs[r0 + 2], x3 = xs[r0 + 3];
  const float p0 = fmaf(-5.f, x2[r0], fmaf(-10.f, fc[r0], logf(xw[r0])));
  const float p1 = fmaf(-5.f, x2[r0 + 1], fmaf(-10.f, fc[r0 + 1], logf(xw[r0 + 1])));
  const float p2 = fmaf(-5.f, x2[r0 + 2], fmaf(-10.f, fc[r0 + 2], logf(xw[r0 + 2])));
  const float p3 = fmaf(-5.f, x2[r0 + 3], fmaf(-10.f, fc[r0 + 3], logf(xw[r0 + 3])));
  float a0 = 0.f, a1 = 0.f, a2 = 0.f, a3 = 0.f;
#pragma unroll 4
  for (int t = 0; t < 64; ++t) {
    const int j = (t << 6) + lane;
    const float yx = yxs[j], yy = yys[j], w = P[j];
    a0 += __expf(fmaf(F_IEPS, fmaf(x0.x, yx, x0.y * yy), w + p0));
    a1 += __expf(fmaf(F_IEPS, fmaf(x1.x, yx, x1.y * yy), w + p1));
    a2 += __expf(fmaf(F_IEPS, fmaf(x2v.x, yx, x2v.y * yy), w + p2));
    a3 += __expf(fmaf(F_IEPS, fmaf(x3.x, yx, x3.y * yy), w + p3));
  }
  const float aw = wsum(((a0 + a1) + (a2 + a3)));
  if (lane == 0) red[wib] = aw;
  __syncthreads();
  if (tid == 0) part[bid] = ((red[0] + red[1]) + (red[2] + red[3]));
}

__global__ void final_kernel(const float* fc, const float* gc,
                             const float* xw, const float* yw,
                             const float* part, float* out) {
  __shared__ float r1[256], r2[256], r3[256];
  const int tid = threadIdx.x;
  float a1 = 0.f, a2 = 0.f;
  for (int i = tid; i < N; i += 256) { a1 += fc[i] * xw[i]; a2 += gc[i] * yw[i]; }
  const float a3 = part[tid];   // NBH == 256
  r1[tid] = a1; r2[tid] = a2; r3[tid] = a3; __syncthreads();
  for (int s2 = 128; s2; s2 >>= 1) {
    if (tid < s2) { r1[tid] += r1[tid + s2]; r2[tid] += r2[tid + s2]; r3[tid] += r3[tid + s2]; }
    __syncthreads();
  }
  if (tid == 0) out[0] = -r1[0] - r2[0] - F_EPS * r3[0];
}

extern "C" void kernel_launch(void* const* d_in, const int* in_sizes, int n_in,
                              void* d_out, int out_size, void* d_ws, size_t ws_size,
                              hipStream_t stream) {
  const float*  xw  = (const float*)d_in[0];
  const float2* xs2 = (const float2*)d_in[1];
  const float*  yw  = (const float*)d_in[2];
  const float2* ys2 = (const float2*)d_in[3];
  float* out = (float*)d_out;

  float* w = (float*)d_ws;
  float *u  = w,          *v  = w + 4096,  *av = w + 8192,  *bv = w + 12288,
        *s  = w + 16384,  *x2 = w + 20480, *y2 = w + 24576,
        *ci = w + 28672,  *cj = w + 32768,
        *fc = w + 36864,  *gc = w + 40960,
        *berr = w + 45056, *bu = w + 45568, *part = w + 46080,
        *ywn = w + 46592;
  int* flags = (int*)(w + 46600);
  unsigned* cntC = (unsigned*)(w + 46608);
  unsigned* cntR = (unsigned*)(w + 46616);

  init_kernel<<<1, 256, 0, stream>>>(xw, xs2, yw, ys2, u, v, av, bv, x2, y2, ci, cj,
                                     ywn, flags, cntC, cntR);
  // prelude: s = K^T @ 1
  colpass_kernel<<<NBH, BT, 0, stream>>>(xw, yw, xs2, ys2, ci, cj, u, v,
                                         s, berr, ywn, flags, cntC, 0);
  for (int it = 0; it < NITER; ++it) {
    rowpass_kernel<<<NBH, BT, 0, stream>>>(xw, yw, xs2, ys2, ci, cj, av, bv,
                                           x2, y2, u, v, s, bu, flags, cntR);
    colpass_kernel<<<NBH, BT, 0, stream>>>(xw, yw, xs2, ys2, ci, cj, u, v,
                                           s, berr, ywn, flags, cntC, 1);
  }
  fcts_kernel<<<NBH, BT, 0, stream>>>(xw, yw, xs2, ys2, x2, y2, v, bv, fc);
  gcts_kernel<<<NBH, BT, 0, stream>>>(xw, yw, xs2, ys2, x2, y2, u, av, gc);
  plan_kernel<<<NBH, BT, 0, stream>>>(xw, yw, xs2, ys2, x2, y2, fc, gc, part);
  final_kernel<<<1, 256, 0, stream>>>(fc, gc, xw, yw, part, out);
}

// Round 4
// 321.726 us; speedup vs baseline: 4.6596x; 2.5012x over previous
//
#include <hip/hip_runtime.h>
#include <math.h>

#define N 4096

static constexpr float F_EPS     = 0.1f;
static constexpr float F_IEPS    = 10.0f;                  // 1/EPS
static constexpr float F_LOGZ    = -0.46470802658470073f;  // ln(2*pi*0.1)
static constexpr float F_EPSLOGZ = -0.046470802658470075f; // EPS*LOGZ
static constexpr float F_ATOL    = 1e-4f;
static constexpr float F_RTOL    = 1e-4f;
static constexpr int   NITER     = 200;
static constexpr int   NB        = 256;   // persistent blocks (1 per CU guaranteed resident; 3/CU capacity)
static constexpr int   BT        = 256;   // threads/block (4 waves)
static constexpr int   CPB       = 16;    // rows|cols per block
static constexpr int   CPW       = 4;     // per wave

// ---------- wave helpers (deterministic fixed-order reductions) ----------
__device__ __forceinline__ float wsum(float x) {
#pragma unroll
  for (int o = 32; o; o >>= 1) x += __shfl_xor(x, o, 64);
  return x;
}
__device__ __forceinline__ float wmax(float x) {
#pragma unroll
  for (int o = 32; o; o >>= 1) x = fmaxf(x, __shfl_xor(x, o, 64));
  return x;
}
__device__ __forceinline__ float aload(const float* p) {
  return __hip_atomic_load(p, __ATOMIC_RELAXED, __HIP_MEMORY_SCOPE_AGENT);
}
__device__ __forceinline__ float cost_ij(float2 xi, float x2i, float2 yj, float y2j) {
  const float dot = xi.x * yj.x + xi.y * yj.y;
  return 0.5f * fmaxf(x2i + y2j - 2.0f * dot, 0.0f);
}

// ---------- grid barrier: 16 leaves x 16 blocks -> root -> gen (monotonic) ----------
__device__ __forceinline__ void gbar(unsigned* leaf, unsigned* root, unsigned* gen,
                                     int bid, unsigned target) {
  __threadfence();
  __syncthreads();
  if (threadIdx.x == 0) {
    const unsigned old = __hip_atomic_fetch_add(&leaf[(bid & 15) << 5], 1u,
                                                __ATOMIC_ACQ_REL, __HIP_MEMORY_SCOPE_AGENT);
    if ((old & 15u) == 15u) {
      const unsigned r = __hip_atomic_fetch_add(root, 1u,
                                                __ATOMIC_ACQ_REL, __HIP_MEMORY_SCOPE_AGENT);
      if ((r & 15u) == 15u)
        __hip_atomic_fetch_add(gen, 1u, __ATOMIC_ACQ_REL, __HIP_MEMORY_SCOPE_AGENT);
    }
    while (__hip_atomic_load(gen, __ATOMIC_ACQUIRE, __HIP_MEMORY_SCOPE_AGENT) < target)
      __builtin_amdgcn_s_sleep(2);
  }
  __syncthreads();
}

// ---------- init ----------
__global__ void init_kernel(const float* __restrict__ xw, const float2* __restrict__ xs,
                            const float* __restrict__ yw, const float2* __restrict__ ys,
                            float* u, float* v, float* av, float* bv,
                            float* x2, float* y2, float* ci, float* cj,
                            float* ywn, unsigned* sync) {
  __shared__ float red[256];
  const int tid = threadIdx.x;
  float m = 0.f;
  for (int i = tid; i < N; i += 256) {
    u[i] = 1.f; v[i] = 1.f; av[i] = 0.f; bv[i] = 0.f;
    const float2 a = xs[i]; const float xx = a.x * a.x + a.y * a.y;
    const float2 b = ys[i]; const float yy = b.x * b.x + b.y * b.y;
    x2[i] = xx; y2[i] = yy;
    ci[i] = -F_IEPS * (0.5f * xx);            // -IEPS*(x2/2 + av), av=0
    cj[i] = -F_IEPS * (0.5f * yy) - F_LOGZ;   // -IEPS*(y2/2 + bv) - LOGZ
    m = fmaxf(m, fabsf(yw[i]));
  }
  for (int k = tid; k < 640; k += 256) sync[k] = 0u;
  red[tid] = m; __syncthreads();
  for (int s2 = 128; s2; s2 >>= 1) { if (tid < s2) red[tid] = fmaxf(red[tid], red[tid + s2]); __syncthreads(); }
  if (tid == 0) ywn[0] = red[0];
}

// ---------- persistent Sinkhorn loop (single dispatch, early exit) ----------
__global__ void __launch_bounds__(BT) sink_kernel(
    const float* __restrict__ xw, const float* __restrict__ yw,
    const float2* __restrict__ xs, const float2* __restrict__ ys,
    const float* __restrict__ ci, const float* __restrict__ cj,
    float* __restrict__ u, float* __restrict__ v,
    float* __restrict__ s, float* __restrict__ berr,
    const float* __restrict__ ywn, unsigned* __restrict__ sync) {
  __shared__ __align__(16) float A0[N], A1[N], P[N];   // 48 KiB
  __shared__ float ew[4];
  __shared__ float rt[BT];
  unsigned* leaf = sync;          // 16 counters, stride 32 uints (128 B)
  unsigned* root = sync + 544;
  unsigned* gen  = sync + 576;
  const int tid = threadIdx.x, bid = blockIdx.x;
  const int lane = tid & 63, wib = tid >> 6;
  const int c0 = bid * CPB + wib * CPW;
  const float ywnv = ywn[0];
  unsigned tgt = 0;

  // ---- prelude colpass: s = K^T u (u = 1), no err ----
  for (int k = tid; k < N; k += BT) {
    const float2 p = xs[k];
    A0[k] = p.x; A1[k] = p.y;
    P[k] = ci[k] + logf(xw[k] * aload(&u[k]));
  }
  __syncthreads();
  {
    const float2 y0 = ys[c0], y1 = ys[c0 + 1], y2v = ys[c0 + 2], y3 = ys[c0 + 3];
    float a0 = 0.f, a1 = 0.f, a2 = 0.f, a3 = 0.f;
#pragma unroll 4
    for (int t = 0; t < 64; ++t) {
      const int i = (t << 6) + lane;
      const float xx = A0[i], xy = A1[i], w = P[i];
      a0 += __expf(fmaf(F_IEPS, fmaf(xx, y0.x, xy * y0.y), w));
      a1 += __expf(fmaf(F_IEPS, fmaf(xx, y1.x, xy * y1.y), w));
      a2 += __expf(fmaf(F_IEPS, fmaf(xx, y2v.x, xy * y2v.y), w));
      a3 += __expf(fmaf(F_IEPS, fmaf(xx, y3.x, xy * y3.y), w));
    }
    a0 = wsum(a0); a1 = wsum(a1); a2 = wsum(a2); a3 = wsum(a3);
    if (lane == 0) {
      const float acc[4] = {a0, a1, a2, a3};
#pragma unroll
      for (int q = 0; q < 4; ++q) {
        const int c = c0 + q;
        s[c] = yw[c] * __expf(cj[c]) * acc[q];
      }
    }
  }
  tgt += 1; gbar(leaf, root, gen, bid, tgt);

  for (int it = 0; it < NITER; ++it) {
    // ---- rowpass: v = yw/s (redundant full), u = xw/(K v) ----
    for (int k = tid; k < N; k += BT) {
      const float ywk = yw[k];
      const float vv = ywk / aload(&s[k]);
      if ((k >> 4) == bid) v[k] = vv;            // owned 16-slice
      const float2 p = ys[k];
      A0[k] = p.x; A1[k] = p.y;
      P[k] = cj[k] + logf(ywk * vv);
    }
    __syncthreads();
    {
      const float2 x0 = xs[c0], x1 = xs[c0 + 1], x2v = xs[c0 + 2], x3 = xs[c0 + 3];
      float a0 = 0.f, a1 = 0.f, a2 = 0.f, a3 = 0.f;
#pragma unroll 4
      for (int t = 0; t < 64; ++t) {
        const int j = (t << 6) + lane;
        const float yx = A0[j], yy = A1[j], w = P[j];
        a0 += __expf(fmaf(F_IEPS, fmaf(x0.x, yx, x0.y * yy), w));
        a1 += __expf(fmaf(F_IEPS, fmaf(x1.x, yx, x1.y * yy), w));
        a2 += __expf(fmaf(F_IEPS, fmaf(x2v.x, yx, x2v.y * yy), w));
        a3 += __expf(fmaf(F_IEPS, fmaf(x3.x, yx, x3.y * yy), w));
      }
      a0 = wsum(a0); a1 = wsum(a1); a2 = wsum(a2); a3 = wsum(a3);
      if (lane == 0) {
        const float acc[4] = {a0, a1, a2, a3};
#pragma unroll
        for (int q = 0; q < 4; ++q) {
          const int r = c0 + q;
          const float xr = xw[r];
          const float kv = xr * __expf(ci[r]) * acc[q];   // (K v)_r
          u[r] = xr / kv;
        }
      }
    }
    tgt += 1; gbar(leaf, root, gen, bid, tgt);   // u, v visible

    // ---- colpass: s = K^T u, err partials ----
    for (int k = tid; k < N; k += BT) {
      const float2 p = xs[k];
      A0[k] = p.x; A1[k] = p.y;
      P[k] = ci[k] + logf(xw[k] * aload(&u[k]));
    }
    __syncthreads();
    {
      const float2 y0 = ys[c0], y1 = ys[c0 + 1], y2v = ys[c0 + 2], y3 = ys[c0 + 3];
      float a0 = 0.f, a1 = 0.f, a2 = 0.f, a3 = 0.f;
#pragma unroll 4
      for (int t = 0; t < 64; ++t) {
        const int i = (t << 6) + lane;
        const float xx = A0[i], xy = A1[i], w = P[i];
        a0 += __expf(fmaf(F_IEPS, fmaf(xx, y0.x, xy * y0.y), w));
        a1 += __expf(fmaf(F_IEPS, fmaf(xx, y1.x, xy * y1.y), w));
        a2 += __expf(fmaf(F_IEPS, fmaf(xx, y2v.x, xy * y2v.y), w));
        a3 += __expf(fmaf(F_IEPS, fmaf(xx, y3.x, xy * y3.y), w));
      }
      a0 = wsum(a0); a1 = wsum(a1); a2 = wsum(a2); a3 = wsum(a3);
      if (lane == 0) {
        const float acc[4] = {a0, a1, a2, a3};
        float e = 0.f;
#pragma unroll
        for (int q = 0; q < 4; ++q) {
          const int c = c0 + q;
          const float sc = yw[c] * __expf(cj[c]) * acc[q];
          s[c] = sc;
          e = fmaxf(e, fabsf(aload(&v[c]) * sc - yw[c]));
        }
        ew[wib] = e;
      }
    }
    __syncthreads();
    if (tid == 0) berr[bid] = fmaxf(fmaxf(ew[0], ew[1]), fmaxf(ew[2], ew[3]));
    tgt += 1; gbar(leaf, root, gen, bid, tgt);   // s, berr visible

    // ---- decide (redundant, uniform across all blocks) ----
    rt[tid] = aload(&berr[tid]);                 // NB == BT == 256
    __syncthreads();
    for (int s2 = 128; s2; s2 >>= 1) { if (tid < s2) rt[tid] = fmaxf(rt[tid], rt[tid + s2]); __syncthreads(); }
    const float err = rt[0];
    __syncthreads();
    if ((err < F_ATOL) || (err / ywnv < F_RTOL)) break;
  }
}

// ---------- objective tail (verbatim from round 3; av/bv are zero) ----------
__global__ void __launch_bounds__(BT) fcts_kernel(
    const float* __restrict__ xw, const float* __restrict__ yw,
    const float2* __restrict__ xs, const float2* __restrict__ ys,
    const float* __restrict__ x2, const float* __restrict__ y2,
    const float* __restrict__ v, const float* __restrict__ bv,
    float* __restrict__ fc) {
  __shared__ __align__(16) float yxs[N], yys[N], B[N];
  const int tid = threadIdx.x, bid = blockIdx.x;
  const int lane = tid & 63, wib = tid >> 6;
  for (int k = tid; k < N; k += BT) {
    const float2 p = ys[k];
    yxs[k] = p.x; yys[k] = p.y;
    B[k] = fmaf(-5.f, y2[k], fmaf(-10.f, bv[k], logf(v[k]) + logf(yw[k])));
  }
  __syncthreads();
  const int r0 = bid * CPB + wib * CPW;
  const float2 x0 = xs[r0], x1 = xs[r0 + 1], x2v = xs[r0 + 2], x3 = xs[r0 + 3];
  float m0 = -3.4e38f, m1 = m0, m2 = m0, m3 = m0;
#pragma unroll 4
  for (int t = 0; t < 64; ++t) {
    const int j = (t << 6) + lane;
    const float yx = yxs[j], yy = yys[j], w = B[j];
    m0 = fmaxf(m0, fmaf(F_IEPS, fmaf(x0.x, yx, x0.y * yy), w));
    m1 = fmaxf(m1, fmaf(F_IEPS, fmaf(x1.x, yx, x1.y * yy), w));
    m2 = fmaxf(m2, fmaf(F_IEPS, fmaf(x2v.x, yx, x2v.y * yy), w));
    m3 = fmaxf(m3, fmaf(F_IEPS, fmaf(x3.x, yx, x3.y * yy), w));
  }
  m0 = wmax(m0); m1 = wmax(m1); m2 = wmax(m2); m3 = wmax(m3);
  float s0 = 0.f, s1 = 0.f, s2 = 0.f, s3 = 0.f;
#pragma unroll 4
  for (int t = 0; t < 64; ++t) {
    const int j = (t << 6) + lane;
    const float yx = yxs[j], yy = yys[j], w = B[j];
    s0 += __expf(fmaf(F_IEPS, fmaf(x0.x, yx, x0.y * yy), w) - m0);
    s1 += __expf(fmaf(F_IEPS, fmaf(x1.x, yx, x1.y * yy), w) - m1);
    s2 += __expf(fmaf(F_IEPS, fmaf(x2v.x, yx, x2v.y * yy), w) - m2);
    s3 += __expf(fmaf(F_IEPS, fmaf(x3.x, yx, x3.y * yy), w) - m3);
  }
  s0 = wsum(s0); s1 = wsum(s1); s2 = wsum(s2); s3 = wsum(s3);
  if (lane == 0) {
    const float mm[4] = {m0, m1, m2, m3}; const float ss[4] = {s0, s1, s2, s3};
#pragma unroll
    for (int q = 0; q < 4; ++q) {
      const int r = r0 + q;
      fc[r] = F_EPS * (-5.f * x2[r] + mm[q] + logf(ss[q])) - F_EPSLOGZ;
    }
  }
}

__global__ void __launch_bounds__(BT) gcts_kernel(
    const float* __restrict__ xw, const float* __restrict__ yw,
    const float2* __restrict__ xs, const float2* __restrict__ ys,
    const float* __restrict__ x2, const float* __restrict__ y2,
    const float* __restrict__ u, const float* __restrict__ av,
    float* __restrict__ gc) {
  __shared__ __align__(16) float sx[N], sy[N], B[N];
  const int tid = threadIdx.x, bid = blockIdx.x;
  const int lane = tid & 63, wib = tid >> 6;
  for (int k = tid; k < N; k += BT) {
    const float2 p = xs[k];
    sx[k] = p.x; sy[k] = p.y;
    B[k] = fmaf(-5.f, x2[k], fmaf(-10.f, av[k], logf(u[k]) + logf(xw[k])));
  }
  __syncthreads();
  const int c0 = bid * CPB + wib * CPW;
  const float2 y0 = ys[c0], y1 = ys[c0 + 1], y2v = ys[c0 + 2], y3 = ys[c0 + 3];
  float m0 = -3.4e38f, m1 = m0, m2 = m0, m3 = m0;
#pragma unroll 4
  for (int t = 0; t < 64; ++t) {
    const int i = (t << 6) + lane;
    const float xx = sx[i], xy = sy[i], w = B[i];
    m0 = fmaxf(m0, fmaf(F_IEPS, fmaf(xx, y0.x, xy * y0.y), w));
    m1 = fmaxf(m1, fmaf(F_IEPS, fmaf(xx, y1.x, xy * y1.y), w));
    m2 = fmaxf(m2, fmaf(F_IEPS, fmaf(xx, y2v.x, xy * y2v.y), w));
    m3 = fmaxf(m3, fmaf(F_IEPS, fmaf(xx, y3.x, xy * y3.y), w));
  }
  m0 = wmax(m0); m1 = wmax(m1); m2 = wmax(m2); m3 = wmax(m3);
  float s0 = 0.f, s1 = 0.f, s2 = 0.f, s3 = 0.f;
#pragma unroll 4
  for (int t = 0; t < 64; ++t) {
    const int i = (t << 6) + lane;
    const float xx = sx[i], xy = sy[i], w = B[i];
    s0 += __expf(fmaf(F_IEPS, fmaf(xx, y0.x, xy * y0.y), w) - m0);
    s1 += __expf(fmaf(F_IEPS, fmaf(xx, y1.x, xy * y1.y), w) - m1);
    s2 += __expf(fmaf(F_IEPS, fmaf(xx, y2v.x, xy * y2v.y), w) - m2);
    s3 += __expf(fmaf(F_IEPS, fmaf(xx, y3.x, xy * y3.y), w) - m3);
  }
  s0 = wsum(s0); s1 = wsum(s1); s2 = wsum(s2); s3 = wsum(s3);
  if (lane == 0) {
    const float mm[4] = {m0, m1, m2, m3}; const float ss[4] = {s0, s1, s2, s3};
#pragma unroll
    for (int q = 0; q < 4; ++q) {
      const int c = c0 + q;
      gc[c] = F_EPS * (-5.f * y2[c] + mm[q] + logf(ss[q])) - F_EPSLOGZ;
    }
  }
}

__global__ void __launch_bounds__(BT) plan_kernel(
    const float* __restrict__ xw, const float* __restrict__ yw,
    const float2* __restrict__ xs, const float2* __restrict__ ys,
    const float* __restrict__ x2, const float* __restrict__ y2,
    const float* __restrict__ fc, const float* __restrict__ gc,
    float* __restrict__ part) {
  __shared__ __align__(16) float yxs[N], yys[N], P[N];
  __shared__ float red[4];
  const int tid = threadIdx.x, bid = blockIdx.x;
  const int lane = tid & 63, wib = tid >> 6;
  for (int k = tid; k < N; k += BT) {
    const float2 p = ys[k];
    yxs[k] = p.x; yys[k] = p.y;
    P[k] = fmaf(-5.f, y2[k], fmaf(-10.f, gc[k], logf(yw[k]))) - F_LOGZ;
  }
  __syncthreads();
  const int r0 = bid * CPB + wib * CPW;
  const float2 x0 = xs[r0], x1 = xs[r0 + 1], x2v = xs[r0 + 2], x3 = xs[r0 + 3];
  const float p0 = fmaf(-5.f, x2[r0], fmaf(-10.f, fc[r0], logf(xw[r0])));
  const float p1 = fmaf(-5.f, x2[r0 + 1], fmaf(-10.f, fc[r0 + 1], logf(xw[r0 + 1])));
  const float p2 = fmaf(-5.f, x2[r0 + 2], fmaf(-10.f, fc[r0 + 2], logf(xw[r0 + 2])));
  const float p3 = fmaf(-5.f, x2[r0 + 3], fmaf(-10.f, fc[r0 + 3], logf(xw[r0 + 3])));
  float a0 = 0.f, a1 = 0.f, a2 = 0.f, a3 = 0.f;
#pragma unroll 4
  for (int t = 0; t < 64; ++t) {
    const int j = (t << 6) + lane;
    const float yx = yxs[j], yy = yys[j], w = P[j];
    a0 += __expf(fmaf(F_IEPS, fmaf(x0.x, yx, x0.y * yy), w + p0));
    a1 += __expf(fmaf(F_IEPS, fmaf(x1.x, yx, x1.y * yy), w + p1));
    a2 += __expf(fmaf(F_IEPS, fmaf(x2v.x, yx, x2v.y * yy), w + p2));
    a3 += __expf(fmaf(F_IEPS, fmaf(x3.x, yx, x3.y * yy), w + p3));
  }
  const float aw = wsum(((a0 + a1) + (a2 + a3)));
  if (lane == 0) red[wib] = aw;
  __syncthreads();
  if (tid == 0) part[bid] = ((red[0] + red[1]) + (red[2] + red[3]));
}

__global__ void final_kernel(const float* fc, const float* gc,
                             const float* xw, const float* yw,
                             const float* part, float* out) {
  __shared__ float r1[256], r2[256], r3[256];
  const int tid = threadIdx.x;
  float a1 = 0.f, a2 = 0.f;
  for (int i = tid; i < N; i += 256) { a1 += fc[i] * xw[i]; a2 += gc[i] * yw[i]; }
  const float a3 = part[tid];   // NB == 256
  r1[tid] = a1; r2[tid] = a2; r3[tid] = a3; __syncthreads();
  for (int s2 = 128; s2; s2 >>= 1) {
    if (tid < s2) { r1[tid] += r1[tid + s2]; r2[tid] += r2[tid + s2]; r3[tid] += r3[tid + s2]; }
    __syncthreads();
  }
  if (tid == 0) out[0] = -r1[0] - r2[0] - F_EPS * r3[0];
}

extern "C" void kernel_launch(void* const* d_in, const int* in_sizes, int n_in,
                              void* d_out, int out_size, void* d_ws, size_t ws_size,
                              hipStream_t stream) {
  const float*  xw  = (const float*)d_in[0];
  const float2* xs2 = (const float2*)d_in[1];
  const float*  yw  = (const float*)d_in[2];
  const float2* ys2 = (const float2*)d_in[3];
  float* out = (float*)d_out;

  float* w = (float*)d_ws;
  float *u  = w,          *v  = w + 4096,  *av = w + 8192,  *bv = w + 12288,
        *s  = w + 16384,  *x2 = w + 20480, *y2 = w + 24576,
        *ci = w + 28672,  *cj = w + 32768,
        *fc = w + 36864,  *gc = w + 40960,
        *berr = w + 45056, *part = w + 45312, *ywn = w + 45568;
  unsigned* sync = (unsigned*)(w + 46080);   // 640 uints: leaf[16*32] | root | gen

  init_kernel<<<1, 256, 0, stream>>>(xw, xs2, yw, ys2, u, v, av, bv, x2, y2, ci, cj,
                                     ywn, sync);
  sink_kernel<<<NB, BT, 0, stream>>>(xw, yw, xs2, ys2, ci, cj, u, v, s, berr, ywn, sync);
  fcts_kernel<<<NB, BT, 0, stream>>>(xw, yw, xs2, ys2, x2, y2, v, bv, fc);
  gcts_kernel<<<NB, BT, 0, stream>>>(xw, yw, xs2, ys2, x2, y2, u, av, gc);
  plan_kernel<<<NB, BT, 0, stream>>>(xw, yw, xs2, ys2, x2, y2, fc, gc, part);
  final_kernel<<<1, 256, 0, stream>>>(fc, gc, xw, yw, part, out);
}

// Round 5
// 185.907 us; speedup vs baseline: 8.0637x; 1.7306x over previous
//
#include <hip/hip_runtime.h>
#include <math.h>

#define N 4096

static constexpr float F_EPS     = 0.1f;
static constexpr float F_EPSLOGZ = -0.046470802658470075f; // EPS*LOGZ
static constexpr float F_ATOL    = 1e-4f;
static constexpr float F_RTOL    = 1e-4f;
static constexpr int   NITER     = 200;
static constexpr int   NB        = 256;   // persistent blocks, 1/CU
static constexpr int   BT        = 256;   // 4 waves
static constexpr float L2E       = 1.4426950408889634f;   // log2(e)
static constexpr float K2        = 14.426950408889634f;   // 10*log2(e)  (1/EPS in base-2)
static constexpr float HK2       = 7.213475204444817f;    // 5*log2(e)
static constexpr float C1        = -0.6704311637146724f;  // log2(e)*LOGZ
static constexpr float LN2       = 0.6931471805599453f;

// ---------- wave helpers (deterministic fixed-order) ----------
__device__ __forceinline__ float wsum(float x) {
#pragma unroll
  for (int o = 32; o; o >>= 1) x += __shfl_xor(x, o, 64);
  return x;
}
__device__ __forceinline__ float wmax(float x) {
#pragma unroll
  for (int o = 32; o; o >>= 1) x = fmaxf(x, __shfl_xor(x, o, 64));
  return x;
}

// ---------- relaxed agent-scope (cache-bypassing, coherent) access ----------
__device__ __forceinline__ float aload(const float* p) {
  return __hip_atomic_load(p, __ATOMIC_RELAXED, __HIP_MEMORY_SCOPE_AGENT);
}
__device__ __forceinline__ void astore(float* p, float v) {
  __hip_atomic_store(p, v, __ATOMIC_RELAXED, __HIP_MEMORY_SCOPE_AGENT);
}
__device__ __forceinline__ unsigned uload(const unsigned* p) {
  return __hip_atomic_load(p, __ATOMIC_RELAXED, __HIP_MEMORY_SCOPE_AGENT);
}

// ---------- relaxed tree grid-barrier: no fences, no cache maintenance ----------
// All exchanged data uses relaxed-atomic (uncached) ops, so visibility needs only
// "my stores completed (vmcnt 0) before arrive" + monotonic counters.
__device__ __forceinline__ void gbar(unsigned* sync, int bid, unsigned tgt) {
  asm volatile("s_waitcnt vmcnt(0)" ::: "memory");  // all my global writes fabric-visible
  __syncthreads();
  if (threadIdx.x == 0) {
    unsigned* leaf = sync + ((bid & 15) << 4);   // 16 leaves, 64B apart
    unsigned* root = sync + 256;
    unsigned* gen  = sync + 272;
    const unsigned old = __hip_atomic_fetch_add(leaf, 1u, __ATOMIC_RELAXED, __HIP_MEMORY_SCOPE_AGENT);
    if ((old & 15u) == 15u) {
      const unsigned r = __hip_atomic_fetch_add(root, 1u, __ATOMIC_RELAXED, __HIP_MEMORY_SCOPE_AGENT);
      if ((r & 15u) == 15u)
        __hip_atomic_fetch_add(gen, 1u, __ATOMIC_RELAXED, __HIP_MEMORY_SCOPE_AGENT);
    }
    while (uload(gen) < tgt) __builtin_amdgcn_s_sleep(1);
  }
  __syncthreads();
}

__global__ void zero_kernel(unsigned* sync) {
  const int t = threadIdx.x;
  if (t < 288) __hip_atomic_store(&sync[t], 0u, __ATOMIC_RELAXED, __HIP_MEMORY_SCOPE_AGENT);
}

// ---------- the whole problem in one persistent kernel ----------
__global__ void __launch_bounds__(BT) fused_kernel(
    const float* __restrict__ xw, const float2* __restrict__ xs,
    const float* __restrict__ yw, const float2* __restrict__ ys,
    float* __restrict__ pcol, float* __restrict__ prow, float* __restrict__ psav,
    float* __restrict__ berr, float* __restrict__ fcg, float* __restrict__ gcg,
    float* __restrict__ part, float* __restrict__ out, unsigned* __restrict__ sync) {
  __shared__ __align__(16) float2 xk[N];   // K2 * x coords (32 KB)
  __shared__ __align__(16) float2 yk[N];   // K2 * y coords (32 KB)
  __shared__ __align__(16) float  P[N];    // per-pass log2-offsets (16 KB)
  __shared__ float ew[4];
  const int tid  = threadIdx.x, bid = blockIdx.x;
  const int lane = tid & 63,    wib = tid >> 6;
  const int c0   = bid * 16 + wib * 4;     // 4 owned rows AND 4 owned cols per wave
  unsigned tgt = 0;

  // ==== init phase ====
  float mv = 0.f;
  for (int k = tid; k < N; k += BT) {
    const float2 xp = xs[k];
    const float2 yp = ys[k];
    xk[k] = make_float2(K2 * xp.x, K2 * xp.y);
    yk[k] = make_float2(K2 * yp.x, K2 * yp.y);
    mv = fmaxf(mv, fabsf(yw[k]));
  }
  mv = wmax(mv);
  if (lane == 0) ew[wib] = mv;
  __syncthreads();
  const float ywn = fmaxf(fmaxf(ew[0], ew[1]), fmaxf(ew[2], ew[3]));  // same in all blocks
  __syncthreads();

  float2 xr[4], yc[4];
  float l2xw[4], l2yw[4], ywc[4];
#pragma unroll
  for (int q = 0; q < 4; ++q) {
    xr[q] = xs[c0 + q];
    yc[q] = ys[c0 + q];
    l2xw[q] = log2f(xw[c0 + q]);
    l2yw[q] = log2f(yw[c0 + q]);
    ywc[q]  = yw[c0 + q];
  }
  // seed Pcol (u=1): l2xw - 5*log2e*x2
  if (tid < 16) {
    const int i = bid * 16 + tid;
    const float2 xp = xs[i];
    astore(&pcol[i], log2f(xw[i]) - HK2 * (xp.x * xp.x + xp.y * xp.y));
  }
  tgt++; gbar(sync, bid, tgt);

  // ==== prelude colpass: accPrev = colsum with u=1; write Prow (encodes v1) ====
  float accPrev[4];
  for (int k = tid; k < N; k += BT) P[k] = aload(&pcol[k]);
  __syncthreads();
  {
    float a[4] = {0.f, 0.f, 0.f, 0.f};
#pragma unroll 8
    for (int t = 0; t < 64; ++t) {
      const int i = (t << 6) + lane;
      const float2 c = xk[i]; const float w = P[i];
#pragma unroll
      for (int q = 0; q < 4; ++q)
        a[q] += exp2f(fmaf(c.x, yc[q].x, fmaf(c.y, yc[q].y, w)));
    }
#pragma unroll
    for (int q = 0; q < 4; ++q) {
      a[q] = wsum(a[q]);
      accPrev[q] = a[q];
      if (lane == 0) astore(&prow[c0 + q], l2yw[q] - log2f(a[q]));
    }
  }
  tgt++; gbar(sync, bid, tgt);

  // ==== Sinkhorn loop ====
  int converged = 0;
  for (int it = 0; it < NITER && !converged; ++it) {
    // ---- rowpass: consume Prow (v), produce Pcol (u) ----
    for (int k = tid; k < N; k += BT) {
      const float pv = aload(&prow[k]);
      P[k] = pv;
      if ((k >> 4) == bid) astore(&psav[k], pv);   // save consumed Prow (final v for tails)
    }
    __syncthreads();
    {
      float a[4] = {0.f, 0.f, 0.f, 0.f};
#pragma unroll 8
      for (int t = 0; t < 64; ++t) {
        const int j = (t << 6) + lane;
        const float2 c = yk[j]; const float w = P[j];
#pragma unroll
        for (int q = 0; q < 4; ++q)
          a[q] += exp2f(fmaf(c.x, xr[q].x, fmaf(c.y, xr[q].y, w)));
      }
#pragma unroll
      for (int q = 0; q < 4; ++q) {
        a[q] = wsum(a[q]);
        if (lane == 0) astore(&pcol[c0 + q], l2xw[q] - log2f(a[q]));  // ci cancels exactly
      }
    }
    tgt++; gbar(sync, bid, tgt);

    // ---- colpass: consume Pcol (u), produce Prow (next v) + err ----
    for (int k = tid; k < N; k += BT) P[k] = aload(&pcol[k]);
    __syncthreads();
    {
      float a[4] = {0.f, 0.f, 0.f, 0.f};
#pragma unroll 8
      for (int t = 0; t < 64; ++t) {
        const int i = (t << 6) + lane;
        const float2 c = xk[i]; const float w = P[i];
#pragma unroll
        for (int q = 0; q < 4; ++q)
          a[q] += exp2f(fmaf(c.x, yc[q].x, fmaf(c.y, yc[q].y, w)));
      }
      float e = 0.f;
#pragma unroll
      for (int q = 0; q < 4; ++q) {
        a[q] = wsum(a[q]);
        e = fmaxf(e, ywc[q] * fabsf(a[q] / accPrev[q] - 1.0f));  // == |v*(K^T u)-yw|
        accPrev[q] = a[q];
        if (lane == 0) astore(&prow[c0 + q], l2yw[q] - log2f(a[q]));
      }
      if (lane == 0) ew[wib] = e;
    }
    __syncthreads();
    if (tid == 0) astore(&berr[bid], fmaxf(fmaxf(ew[0], ew[1]), fmaxf(ew[2], ew[3])));
    tgt++; gbar(sync, bid, tgt);

    // ---- decide (redundant + uniform) ----
    float m = wmax(aload(&berr[tid]));   // 4 waves cover berr[0..255]
    if (lane == 0) ew[wib] = m;
    __syncthreads();
    const float err = fmaxf(fmaxf(ew[0], ew[1]), fmaxf(ew[2], ew[3]));
    __syncthreads();
    if ((err < F_ATOL) || (err / ywn < F_RTOL)) converged = 1;
  }

  // ==== phase F: fc (blocks 0-127) / gc (blocks 128-255), 32 each ====
  {
    const int half = bid >> 7;
    const int base = (bid & 127) * 32 + wib * 8;
    if (half == 0) { for (int k = tid; k < N; k += BT) P[k] = aload(&psav[k]) + C1; }
    else           { for (int k = tid; k < N; k += BT) P[k] = aload(&pcol[k]); }
    __syncthreads();
    float2 rc[8]; float sq2[8]; float acc[8];
#pragma unroll
    for (int q = 0; q < 8; ++q) {
      const int r = base + q;
      rc[q] = half ? ys[r] : xs[r];
      sq2[q] = rc[q].x * rc[q].x + rc[q].y * rc[q].y;
      acc[q] = 0.f;
    }
    if (half == 0) {
#pragma unroll 4
      for (int t = 0; t < 64; ++t) {
        const int j = (t << 6) + lane;
        const float2 c = yk[j]; const float w = P[j];
#pragma unroll
        for (int q = 0; q < 8; ++q)
          acc[q] += exp2f(fmaf(c.x, rc[q].x, fmaf(c.y, rc[q].y, w)));
      }
    } else {
#pragma unroll 4
      for (int t = 0; t < 64; ++t) {
        const int i = (t << 6) + lane;
        const float2 c = xk[i]; const float w = P[i];
#pragma unroll
        for (int q = 0; q < 8; ++q)
          acc[q] += exp2f(fmaf(c.x, rc[q].x, fmaf(c.y, rc[q].y, w)));
      }
    }
#pragma unroll
    for (int q = 0; q < 8; ++q) acc[q] = wsum(acc[q]);
    if (lane == 0) {
#pragma unroll
      for (int q = 0; q < 8; ++q) {
        const int r = base + q;
        const float val = F_EPS * fmaf(LN2, log2f(acc[q]), -5.f * sq2[q]) - F_EPSLOGZ;
        astore(half ? &gcg[r] : &fcg[r], val);
      }
    }
  }
  tgt++; gbar(sync, bid, tgt);

  // ==== phase P: plan partial sums (16 rows/block) ====
  {
    for (int k = tid; k < N; k += BT) {
      const float2 yp = ys[k];
      const float y2k = yp.x * yp.x + yp.y * yp.y;
      P[k] = fmaf(-HK2, y2k, fmaf(-K2, aload(&gcg[k]), log2f(yw[k]))) - C1;
    }
    __syncthreads();
    float a[4], wx[4];
#pragma unroll
    for (int q = 0; q < 4; ++q) {
      const int r = c0 + q;
      const float x2r = xr[q].x * xr[q].x + xr[q].y * xr[q].y;
      wx[q] = fmaf(-HK2, x2r, fmaf(-K2, aload(&fcg[r]), l2xw[q]));
      a[q] = 0.f;
    }
#pragma unroll 8
    for (int t = 0; t < 64; ++t) {
      const int j = (t << 6) + lane;
      const float2 c = yk[j]; const float w = P[j];
#pragma unroll
      for (int q = 0; q < 4; ++q)
        a[q] += exp2f(fmaf(c.x, xr[q].x, fmaf(c.y, xr[q].y, w)));
    }
#pragma unroll
    for (int q = 0; q < 4; ++q) a[q] = wsum(a[q]);
    if (lane == 0)
      ew[wib] = ((exp2f(wx[0]) * a[0] + exp2f(wx[1]) * a[1]) +
                 (exp2f(wx[2]) * a[2] + exp2f(wx[3]) * a[3]));
    __syncthreads();
    if (tid == 0) astore(&part[bid], (ew[0] + ew[1]) + (ew[2] + ew[3]));
  }
  tgt++; gbar(sync, bid, tgt);

  // ==== final: block 0 reduces everything ====
  if (bid == 0) {
    float a1 = 0.f, a2 = 0.f;
    for (int i = tid; i < N; i += BT) {
      a1 += aload(&fcg[i]) * xw[i];
      a2 += aload(&gcg[i]) * yw[i];
    }
    const float a3 = aload(&part[tid]);   // NB == BT
    float* r1 = P; float* r2 = P + 256; float* r3 = P + 512;
    r1[tid] = a1; r2[tid] = a2; r3[tid] = a3; __syncthreads();
    for (int s2 = 128; s2; s2 >>= 1) {
      if (tid < s2) { r1[tid] += r1[tid + s2]; r2[tid] += r2[tid + s2]; r3[tid] += r3[tid + s2]; }
      __syncthreads();
    }
    if (tid == 0) out[0] = -r1[0] - r2[0] - F_EPS * r3[0];
  }
}

extern "C" void kernel_launch(void* const* d_in, const int* in_sizes, int n_in,
                              void* d_out, int out_size, void* d_ws, size_t ws_size,
                              hipStream_t stream) {
  const float*  xw  = (const float*)d_in[0];
  const float2* xs2 = (const float2*)d_in[1];
  const float*  yw  = (const float*)d_in[2];
  const float2* ys2 = (const float2*)d_in[3];
  float* out = (float*)d_out;

  float* w = (float*)d_ws;
  float *pcol = w,          *prow = w + 4096,  *psav = w + 8192,
        *fcg  = w + 12288,  *gcg  = w + 16384,
        *berr = w + 20480,  *part = w + 20736;
  unsigned* sync = (unsigned*)(w + 20992);   // 288 uints

  zero_kernel<<<1, 320, 0, stream>>>(sync);
  fused_kernel<<<NB, BT, 0, stream>>>(xw, xs2, yw, ys2,
                                      pcol, prow, psav, berr, fcg, gcg, part, out, sync);
}

// Round 6
// 144.537 us; speedup vs baseline: 10.3718x; 1.2862x over previous
//
#include <hip/hip_runtime.h>
#include <math.h>

#define N 4096

static constexpr float F_EPS     = 0.1f;
static constexpr float F_EPSLOGZ = -0.046470802658470075f; // EPS*LOGZ
static constexpr float F_ATOL    = 1e-4f;
static constexpr float F_RTOL    = 1e-4f;
static constexpr int   NITER     = 200;
static constexpr int   NB        = 256;   // persistent blocks, 1/CU
static constexpr int   BT        = 256;   // 4 waves
static constexpr float K2        = 14.426950408889634f;   // 10*log2(e)
static constexpr float HK2       = 7.213475204444817f;    // 5*log2(e)
static constexpr float C1        = -0.6704311637146724f;  // log2(e)*LOGZ
static constexpr float LN2       = 0.6931471805599453f;

// ---------- wave helpers (deterministic fixed-order) ----------
__device__ __forceinline__ float wsum(float x) {
#pragma unroll
  for (int o = 32; o; o >>= 1) x += __shfl_xor(x, o, 64);
  return x;
}
__device__ __forceinline__ float wmax(float x) {
#pragma unroll
  for (int o = 32; o; o >>= 1) x = fmaxf(x, __shfl_xor(x, o, 64));
  return x;
}

// ---------- relaxed agent-scope (cache-bypassing, coherent) access ----------
__device__ __forceinline__ float aload(const float* p) {
  return __hip_atomic_load(p, __ATOMIC_RELAXED, __HIP_MEMORY_SCOPE_AGENT);
}
__device__ __forceinline__ void astore(float* p, float v) {
  __hip_atomic_store(p, v, __ATOMIC_RELAXED, __HIP_MEMORY_SCOPE_AGENT);
}
__device__ __forceinline__ unsigned uload(const unsigned* p) {
  return __hip_atomic_load(p, __ATOMIC_RELAXED, __HIP_MEMORY_SCOPE_AGENT);
}

// ---------- relaxed tree grid-barrier with replicated-flag release ----------
// sync layout (uints): leaf[16] @ stride 16 (0..255) | root @256 | flag[16] @ stride 16 (272..527)
__device__ __forceinline__ void gbar(unsigned* sync, int bid, unsigned tgt) {
  asm volatile("s_waitcnt vmcnt(0)" ::: "memory");  // my global writes fabric-visible
  __syncthreads();
  if (threadIdx.x == 0) {
    unsigned* leaf = sync + ((bid & 15) << 4);
    unsigned* root = sync + 256;
    unsigned* flag = sync + 272 + ((bid & 15) << 4);
    const unsigned old = __hip_atomic_fetch_add(leaf, 1u, __ATOMIC_RELAXED, __HIP_MEMORY_SCOPE_AGENT);
    if ((old & 15u) == 15u) {
      const unsigned r = __hip_atomic_fetch_add(root, 1u, __ATOMIC_RELAXED, __HIP_MEMORY_SCOPE_AGENT);
      if ((r & 15u) == 15u) {
#pragma unroll
        for (int q = 0; q < 16; ++q)
          __hip_atomic_store(sync + 272 + (q << 4), tgt, __ATOMIC_RELAXED, __HIP_MEMORY_SCOPE_AGENT);
      }
    }
    while (uload(flag) < tgt) __builtin_amdgcn_s_sleep(2);
  }
  __syncthreads();
}

__global__ void zero_kernel(unsigned* sync) {
  const int t = threadIdx.x;
  if (t < 544) __hip_atomic_store(&sync[t], 0u, __ATOMIC_RELAXED, __HIP_MEMORY_SCOPE_AGENT);
}

// ---------- the whole problem in one persistent kernel ----------
__global__ void __launch_bounds__(BT) fused_kernel(
    const float* __restrict__ xw, const float2* __restrict__ xs,
    const float* __restrict__ yw, const float2* __restrict__ ys,
    float* __restrict__ pcol, float* __restrict__ prow, float* __restrict__ psav,
    float* __restrict__ berr, float* __restrict__ fcg, float* __restrict__ gcg,
    float* __restrict__ part, float* __restrict__ out, unsigned* __restrict__ sync) {
  __shared__ __align__(16) float2 xk[N];   // K2 * x coords (32 KB)
  __shared__ __align__(16) float2 yk[N];   // K2 * y coords (32 KB)
  __shared__ __align__(16) float  P[N];    // per-pass log2-offsets (16 KB)
  __shared__ float ew[4];
  const int tid  = threadIdx.x, bid = blockIdx.x;
  const int lane = tid & 63,    wib = tid >> 6;
  const int c0   = bid * 16 + wib * 4;     // 4 owned rows AND 4 owned cols per wave
  unsigned tgt = 0;

  // ==== init: coords->LDS, ywn, and prelude P (u=1 seed) computed locally ====
  float mv = 0.f;
  for (int k = tid; k < N; k += BT) {
    const float2 xp = xs[k];
    const float2 yp = ys[k];
    xk[k] = make_float2(K2 * xp.x, K2 * xp.y);
    yk[k] = make_float2(K2 * yp.x, K2 * yp.y);
    P[k]  = log2f(xw[k]) - HK2 * (xp.x * xp.x + xp.y * xp.y);  // seed: l2xw - 5*log2e*x2
    mv = fmaxf(mv, fabsf(yw[k]));
  }
  mv = wmax(mv);
  if (lane == 0) ew[wib] = mv;
  __syncthreads();
  const float ywn = fmaxf(fmaxf(ew[0], ew[1]), fmaxf(ew[2], ew[3]));  // same in all blocks
  __syncthreads();

  float2 xr[4], yc[4];
  float l2xw[4], l2yw[4], ywc[4];
#pragma unroll
  for (int q = 0; q < 4; ++q) {
    xr[q] = xs[c0 + q];
    yc[q] = ys[c0 + q];
    l2xw[q] = log2f(xw[c0 + q]);
    l2yw[q] = log2f(yw[c0 + q]);
    ywc[q]  = yw[c0 + q];
  }

  // ==== prelude colpass: accPrev = colsum with u=1; write Prow (encodes v1) ====
  float accPrev[4];
  {
    float a[4] = {0.f, 0.f, 0.f, 0.f};
#pragma unroll 8
    for (int t = 0; t < 64; ++t) {
      const int i = (t << 6) + lane;
      const float2 c = xk[i]; const float w = P[i];
#pragma unroll
      for (int q = 0; q < 4; ++q)
        a[q] += exp2f(fmaf(c.x, yc[q].x, fmaf(c.y, yc[q].y, w)));
    }
#pragma unroll
    for (int q = 0; q < 4; ++q) {
      a[q] = wsum(a[q]);
      accPrev[q] = a[q];
      if (lane == 0) astore(&prow[c0 + q], l2yw[q] - log2f(a[q]));
    }
  }
  tgt++; gbar(sync, bid, tgt);

  // ==== Sinkhorn loop ====
  int converged = 0;
  for (int it = 0; it < NITER && !converged; ++it) {
    // ---- rowpass: consume Prow (v), produce Pcol (u) ----
    {
      float tmp[16];
#pragma unroll
      for (int q = 0; q < 16; ++q) tmp[q] = aload(&prow[tid + (q << 8)]);
#pragma unroll
      for (int q = 0; q < 16; ++q) P[tid + (q << 8)] = tmp[q];
    }
    __syncthreads();
    if (tid < 16) astore(&psav[(bid << 4) + tid], P[(bid << 4) + tid]);  // save consumed v
    {
      float a[4] = {0.f, 0.f, 0.f, 0.f};
#pragma unroll 8
      for (int t = 0; t < 64; ++t) {
        const int j = (t << 6) + lane;
        const float2 c = yk[j]; const float w = P[j];
#pragma unroll
        for (int q = 0; q < 4; ++q)
          a[q] += exp2f(fmaf(c.x, xr[q].x, fmaf(c.y, xr[q].y, w)));
      }
#pragma unroll
      for (int q = 0; q < 4; ++q) {
        a[q] = wsum(a[q]);
        if (lane == 0) astore(&pcol[c0 + q], l2xw[q] - log2f(a[q]));  // ci cancels exactly
      }
    }
    tgt++; gbar(sync, bid, tgt);

    // ---- colpass: consume Pcol (u), produce Prow (next v) + err ----
    {
      float tmp[16];
#pragma unroll
      for (int q = 0; q < 16; ++q) tmp[q] = aload(&pcol[tid + (q << 8)]);
#pragma unroll
      for (int q = 0; q < 16; ++q) P[tid + (q << 8)] = tmp[q];
    }
    __syncthreads();
    {
      float a[4] = {0.f, 0.f, 0.f, 0.f};
#pragma unroll 8
      for (int t = 0; t < 64; ++t) {
        const int i = (t << 6) + lane;
        const float2 c = xk[i]; const float w = P[i];
#pragma unroll
        for (int q = 0; q < 4; ++q)
          a[q] += exp2f(fmaf(c.x, yc[q].x, fmaf(c.y, yc[q].y, w)));
      }
      float e = 0.f;
#pragma unroll
      for (int q = 0; q < 4; ++q) {
        a[q] = wsum(a[q]);
        e = fmaxf(e, ywc[q] * fabsf(a[q] / accPrev[q] - 1.0f));  // == |v*(K^T u)-yw|
        accPrev[q] = a[q];
        if (lane == 0) astore(&prow[c0 + q], l2yw[q] - log2f(a[q]));
      }
      if (lane == 0) ew[wib] = e;
    }
    __syncthreads();
    if (tid == 0) astore(&berr[bid], fmaxf(fmaxf(ew[0], ew[1]), fmaxf(ew[2], ew[3])));
    tgt++; gbar(sync, bid, tgt);

    // ---- decide (redundant + uniform) ----
    float m = wmax(aload(&berr[tid]));   // 4 waves cover berr[0..255]
    if (lane == 0) ew[wib] = m;
    __syncthreads();
    const float err = fmaxf(fmaxf(ew[0], ew[1]), fmaxf(ew[2], ew[3]));
    __syncthreads();
    if ((err < F_ATOL) || (err / ywn < F_RTOL)) converged = 1;
  }

  // ==== phase F: fc (blocks 0-127) / gc (blocks 128-255), 32 each ====
  {
    const int half = bid >> 7;
    const int base = (bid & 127) * 32 + wib * 8;
    {
      float tmp[16];
      if (half == 0) {
#pragma unroll
        for (int q = 0; q < 16; ++q) tmp[q] = aload(&psav[tid + (q << 8)]) + C1;
      } else {
#pragma unroll
        for (int q = 0; q < 16; ++q) tmp[q] = aload(&pcol[tid + (q << 8)]);
      }
#pragma unroll
      for (int q = 0; q < 16; ++q) P[tid + (q << 8)] = tmp[q];
    }
    __syncthreads();
    float2 rc[8]; float sq2[8]; float acc[8];
#pragma unroll
    for (int q = 0; q < 8; ++q) {
      const int r = base + q;
      rc[q] = half ? ys[r] : xs[r];
      sq2[q] = rc[q].x * rc[q].x + rc[q].y * rc[q].y;
      acc[q] = 0.f;
    }
    if (half == 0) {
#pragma unroll 4
      for (int t = 0; t < 64; ++t) {
        const int j = (t << 6) + lane;
        const float2 c = yk[j]; const float w = P[j];
#pragma unroll
        for (int q = 0; q < 8; ++q)
          acc[q] += exp2f(fmaf(c.x, rc[q].x, fmaf(c.y, rc[q].y, w)));
      }
    } else {
#pragma unroll 4
      for (int t = 0; t < 64; ++t) {
        const int i = (t << 6) + lane;
        const float2 c = xk[i]; const float w = P[i];
#pragma unroll
        for (int q = 0; q < 8; ++q)
          acc[q] += exp2f(fmaf(c.x, rc[q].x, fmaf(c.y, rc[q].y, w)));
      }
    }
#pragma unroll
    for (int q = 0; q < 8; ++q) acc[q] = wsum(acc[q]);
    if (lane == 0) {
#pragma unroll
      for (int q = 0; q < 8; ++q) {
        const int r = base + q;
        const float val = F_EPS * fmaf(LN2, log2f(acc[q]), -5.f * sq2[q]) - F_EPSLOGZ;
        astore(half ? &gcg[r] : &fcg[r], val);
      }
    }
  }
  tgt++; gbar(sync, bid, tgt);

  // ==== phase P: plan partial sums (16 rows/block) ====
  {
    {
      float tmp[16];
#pragma unroll
      for (int q = 0; q < 16; ++q) tmp[q] = aload(&gcg[tid + (q << 8)]);
#pragma unroll
      for (int q = 0; q < 16; ++q) {
        const int k = tid + (q << 8);
        const float2 yp = ys[k];
        const float y2k = yp.x * yp.x + yp.y * yp.y;
        P[k] = fmaf(-HK2, y2k, fmaf(-K2, tmp[q], log2f(yw[k]))) - C1;
      }
    }
    __syncthreads();
    float a[4], wx[4];
#pragma unroll
    for (int q = 0; q < 4; ++q) {
      const int r = c0 + q;
      const float x2r = xr[q].x * xr[q].x + xr[q].y * xr[q].y;
      wx[q] = fmaf(-HK2, x2r, fmaf(-K2, aload(&fcg[r]), l2xw[q]));
      a[q] = 0.f;
    }
#pragma unroll 8
    for (int t = 0; t < 64; ++t) {
      const int j = (t << 6) + lane;
      const float2 c = yk[j]; const float w = P[j];
#pragma unroll
      for (int q = 0; q < 4; ++q)
        a[q] += exp2f(fmaf(c.x, xr[q].x, fmaf(c.y, xr[q].y, w)));
    }
#pragma unroll
    for (int q = 0; q < 4; ++q) a[q] = wsum(a[q]);
    if (lane == 0)
      ew[wib] = ((exp2f(wx[0]) * a[0] + exp2f(wx[1]) * a[1]) +
                 (exp2f(wx[2]) * a[2] + exp2f(wx[3]) * a[3]));
    __syncthreads();
    if (tid == 0) astore(&part[bid], (ew[0] + ew[1]) + (ew[2] + ew[3]));
  }
  tgt++; gbar(sync, bid, tgt);

  // ==== final: block 0 reduces everything ====
  if (bid == 0) {
    float a1 = 0.f, a2 = 0.f;
    for (int i = tid; i < N; i += BT) {
      a1 += aload(&fcg[i]) * xw[i];
      a2 += aload(&gcg[i]) * yw[i];
    }
    const float a3 = aload(&part[tid]);   // NB == BT
    float* r1 = P; float* r2 = P + 256; float* r3 = P + 512;
    r1[tid] = a1; r2[tid] = a2; r3[tid] = a3; __syncthreads();
    for (int s2 = 128; s2; s2 >>= 1) {
      if (tid < s2) { r1[tid] += r1[tid + s2]; r2[tid] += r2[tid + s2]; r3[tid] += r3[tid + s2]; }
      __syncthreads();
    }
    if (tid == 0) out[0] = -r1[0] - r2[0] - F_EPS * r3[0];
  }
}

extern "C" void kernel_launch(void* const* d_in, const int* in_sizes, int n_in,
                              void* d_out, int out_size, void* d_ws, size_t ws_size,
                              hipStream_t stream) {
  const float*  xw  = (const float*)d_in[0];
  const float2* xs2 = (const float2*)d_in[1];
  const float*  yw  = (const float*)d_in[2];
  const float2* ys2 = (const float2*)d_in[3];
  float* out = (float*)d_out;

  float* w = (float*)d_ws;
  float *pcol = w,          *prow = w + 4096,  *psav = w + 8192,
        *fcg  = w + 12288,  *gcg  = w + 16384,
        *berr = w + 20480,  *part = w + 20736;
  unsigned* sync = (unsigned*)(w + 20992);   // 544 uints: leaf[16*16] | root | flag[16*16]

  zero_kernel<<<1, 576, 0, stream>>>(sync);
  fused_kernel<<<NB, BT, 0, stream>>>(xw, xs2, yw, ys2,
                                      pcol, prow, psav, berr, fcg, gcg, part, out, sync);
}

// Round 7
// 139.484 us; speedup vs baseline: 10.7475x; 1.0362x over previous
//
#include <hip/hip_runtime.h>
#include <math.h>

#define N 4096

static constexpr float F_EPS     = 0.1f;
static constexpr float F_EPSLOGZ = -0.046470802658470075f; // EPS*LOGZ
static constexpr float F_ATOL    = 1e-4f;
static constexpr float F_RTOL    = 1e-4f;
static constexpr int   NITER     = 200;
static constexpr int   NB        = 256;   // persistent blocks, 1/CU
static constexpr int   BT        = 256;   // 4 waves
static constexpr float K2        = 14.426950408889634f;   // 10*log2(e)
static constexpr float HK2       = 7.213475204444817f;    // 5*log2(e)
static constexpr float C1        = -0.6704311637146724f;  // log2(e)*LOGZ
static constexpr float LN2       = 0.6931471805599453f;
static constexpr unsigned SALT   = 0x40000000u;  // epoch salt: never collides with 0xAAAAAAAA poison or 0

// ---------- wave helpers (deterministic fixed-order) ----------
__device__ __forceinline__ float wsum(float x) {
#pragma unroll
  for (int o = 32; o; o >>= 1) x += __shfl_xor(x, o, 64);
  return x;
}
__device__ __forceinline__ float wmax(float x) {
#pragma unroll
  for (int o = 32; o; o >>= 1) x = fmaxf(x, __shfl_xor(x, o, 64));
  return x;
}

// ---------- relaxed agent-scope (cache-bypassing, coherent) access ----------
__device__ __forceinline__ float aload(const float* p) {
  return __hip_atomic_load(p, __ATOMIC_RELAXED, __HIP_MEMORY_SCOPE_AGENT);
}
__device__ __forceinline__ void astore(float* p, float v) {
  __hip_atomic_store(p, v, __ATOMIC_RELAXED, __HIP_MEMORY_SCOPE_AGENT);
}
__device__ __forceinline__ unsigned uload(const unsigned* p) {
  return __hip_atomic_load(p, __ATOMIC_RELAXED, __HIP_MEMORY_SCOPE_AGENT);
}
__device__ __forceinline__ void ustore(unsigned* p, unsigned v) {
  __hip_atomic_store(p, v, __ATOMIC_RELAXED, __HIP_MEMORY_SCOPE_AGENT);
}

// ---------- poison-tolerant flat grid-barrier with decide-fold ----------
// sync layout (uints): arrive[256] @ stride 4 (0..1023) | flag[16] @ stride 16 (1024..1279)
// Arrival: fire-and-forget uncached store of SALT+tgt (equality check => any initial
// ws poison value is "not arrived"; no zeroing kernel required).
// Block 0 detects (one slot per thread), optionally reduces berr and folds the
// convergence bit into the 16 replicated release flags. Returns done-bit.
__device__ __forceinline__ int gbar(unsigned* __restrict__ sync, const float* __restrict__ berr,
                                    float* __restrict__ sred, int* __restrict__ sdone,
                                    int bid, int tid, int lane, int wib,
                                    unsigned tgt, int decide, float ywn) {
  asm volatile("s_waitcnt vmcnt(0)" ::: "memory");  // my global writes fabric-visible
  __syncthreads();
  if (tid == 0) ustore(&sync[bid << 2], SALT + tgt);
  if (bid == 0) {
    // detect: each thread spins on its own block's arrival slot
    while (uload(&sync[tid << 2]) != SALT + tgt) __builtin_amdgcn_s_sleep(1);
    __syncthreads();
    unsigned rel = SALT + (tgt << 1);
    if (decide) {
      const float m = wmax(aload(&berr[tid]));
      if (lane == 0) sred[wib] = m;
      __syncthreads();
      const float err = fmaxf(fmaxf(sred[0], sred[1]), fmaxf(sred[2], sred[3]));
      if ((err < F_ATOL) || (err / ywn < F_RTOL)) rel |= 1u;
      __syncthreads();
    }
    if (tid < 16) ustore(&sync[1024 + (tid << 4)], rel);
  }
  if (tid == 0) {
    unsigned f;
    unsigned* flag = &sync[1024 + ((bid & 15) << 4)];
    while (((f = uload(flag)) & ~1u) != SALT + (tgt << 1)) __builtin_amdgcn_s_sleep(1);
    *sdone = (int)(f & 1u);
  }
  __syncthreads();
  return *sdone;
}

// ---------- the whole problem in one persistent kernel (single dispatch) ----------
__global__ void __launch_bounds__(BT) fused_kernel(
    const float* __restrict__ xw, const float2* __restrict__ xs,
    const float* __restrict__ yw, const float2* __restrict__ ys,
    float* __restrict__ pcol, float* __restrict__ prow, float* __restrict__ psav,
    float* __restrict__ berr, float* __restrict__ fcg, float* __restrict__ gcg,
    float* __restrict__ part, float* __restrict__ out, unsigned* __restrict__ sync) {
  __shared__ __align__(16) float2 xk[N];   // K2 * x coords (32 KB)
  __shared__ __align__(16) float2 yk[N];   // K2 * y coords (32 KB)
  __shared__ __align__(16) float  P[N];    // per-pass log2-offsets (16 KB)
  __shared__ float ew[4];
  __shared__ float sred[4];
  __shared__ int   sdone;
  const int tid  = threadIdx.x, bid = blockIdx.x;
  const int lane = tid & 63,    wib = tid >> 6;
  const int c0   = bid * 16 + wib * 4;     // 4 owned rows AND 4 owned cols per wave
  unsigned tgt = 0;

  // ==== init: coords->LDS, ywn, and prelude P (u=1 seed) computed locally ====
  float mv = 0.f;
  for (int k = tid; k < N; k += BT) {
    const float2 xp = xs[k];
    const float2 yp = ys[k];
    xk[k] = make_float2(K2 * xp.x, K2 * xp.y);
    yk[k] = make_float2(K2 * yp.x, K2 * yp.y);
    P[k]  = log2f(xw[k]) - HK2 * (xp.x * xp.x + xp.y * xp.y);  // seed: l2xw - 5*log2e*x2
    mv = fmaxf(mv, fabsf(yw[k]));
  }
  mv = wmax(mv);
  if (lane == 0) ew[wib] = mv;
  __syncthreads();
  const float ywn = fmaxf(fmaxf(ew[0], ew[1]), fmaxf(ew[2], ew[3]));  // same in all blocks
  __syncthreads();

  float2 xr[4], yc[4];
  float l2xw[4], l2yw[4], ywc[4];
#pragma unroll
  for (int q = 0; q < 4; ++q) {
    xr[q] = xs[c0 + q];
    yc[q] = ys[c0 + q];
    l2xw[q] = log2f(xw[c0 + q]);
    l2yw[q] = log2f(yw[c0 + q]);
    ywc[q]  = yw[c0 + q];
  }

  // ==== prelude colpass: accPrev = colsum with u=1; write Prow (encodes v1) ====
  float accPrev[4];
  {
    float a[4] = {0.f, 0.f, 0.f, 0.f};
#pragma unroll 8
    for (int t = 0; t < 64; ++t) {
      const int i = (t << 6) + lane;
      const float2 c = xk[i]; const float w = P[i];
#pragma unroll
      for (int q = 0; q < 4; ++q)
        a[q] += exp2f(fmaf(c.x, yc[q].x, fmaf(c.y, yc[q].y, w)));
    }
#pragma unroll
    for (int q = 0; q < 4; ++q) {
      a[q] = wsum(a[q]);
      accPrev[q] = a[q];
      if (lane == 0) astore(&prow[c0 + q], l2yw[q] - log2f(a[q]));
    }
  }
  tgt++; gbar(sync, berr, sred, &sdone, bid, tid, lane, wib, tgt, 0, ywn);

  // ==== Sinkhorn loop ====
  int converged = 0;
  for (int it = 0; it < NITER && !converged; ++it) {
    // ---- rowpass: consume Prow (v), produce Pcol (u) ----
    {
      float tmp[16];
#pragma unroll
      for (int q = 0; q < 16; ++q) tmp[q] = aload(&prow[tid + (q << 8)]);
#pragma unroll
      for (int q = 0; q < 16; ++q) P[tid + (q << 8)] = tmp[q];
    }
    __syncthreads();
    if (tid < 16) astore(&psav[(bid << 4) + tid], P[(bid << 4) + tid]);  // save consumed v
    {
      float a[4] = {0.f, 0.f, 0.f, 0.f};
#pragma unroll 8
      for (int t = 0; t < 64; ++t) {
        const int j = (t << 6) + lane;
        const float2 c = yk[j]; const float w = P[j];
#pragma unroll
        for (int q = 0; q < 4; ++q)
          a[q] += exp2f(fmaf(c.x, xr[q].x, fmaf(c.y, xr[q].y, w)));
      }
#pragma unroll
      for (int q = 0; q < 4; ++q) {
        a[q] = wsum(a[q]);
        if (lane == 0) astore(&pcol[c0 + q], l2xw[q] - log2f(a[q]));  // ci cancels exactly
      }
    }
    tgt++; gbar(sync, berr, sred, &sdone, bid, tid, lane, wib, tgt, 0, ywn);

    // ---- colpass: consume Pcol (u), produce Prow (next v) + err ----
    {
      float tmp[16];
#pragma unroll
      for (int q = 0; q < 16; ++q) tmp[q] = aload(&pcol[tid + (q << 8)]);
#pragma unroll
      for (int q = 0; q < 16; ++q) P[tid + (q << 8)] = tmp[q];
    }
    __syncthreads();
    {
      float a[4] = {0.f, 0.f, 0.f, 0.f};
#pragma unroll 8
      for (int t = 0; t < 64; ++t) {
        const int i = (t << 6) + lane;
        const float2 c = xk[i]; const float w = P[i];
#pragma unroll
        for (int q = 0; q < 4; ++q)
          a[q] += exp2f(fmaf(c.x, yc[q].x, fmaf(c.y, yc[q].y, w)));
      }
      float e = 0.f;
#pragma unroll
      for (int q = 0; q < 4; ++q) {
        a[q] = wsum(a[q]);
        e = fmaxf(e, ywc[q] * fabsf(a[q] / accPrev[q] - 1.0f));  // == |v*(K^T u)-yw|
        accPrev[q] = a[q];
        if (lane == 0) astore(&prow[c0 + q], l2yw[q] - log2f(a[q]));
      }
      if (lane == 0) ew[wib] = e;
    }
    __syncthreads();
    if (tid == 0) astore(&berr[bid], fmaxf(fmaxf(ew[0], ew[1]), fmaxf(ew[2], ew[3])));
    tgt++;
    converged = gbar(sync, berr, sred, &sdone, bid, tid, lane, wib, tgt, 1, ywn);
  }

  // ==== phase F: fc (blocks 0-127) / gc (blocks 128-255), 32 each ====
  {
    const int half = bid >> 7;
    const int base = (bid & 127) * 32 + wib * 8;
    {
      float tmp[16];
      if (half == 0) {
#pragma unroll
        for (int q = 0; q < 16; ++q) tmp[q] = aload(&psav[tid + (q << 8)]) + C1;
      } else {
#pragma unroll
        for (int q = 0; q < 16; ++q) tmp[q] = aload(&pcol[tid + (q << 8)]);
      }
#pragma unroll
      for (int q = 0; q < 16; ++q) P[tid + (q << 8)] = tmp[q];
    }
    __syncthreads();
    float2 rc[8]; float sq2[8]; float acc[8];
#pragma unroll
    for (int q = 0; q < 8; ++q) {
      const int r = base + q;
      rc[q] = half ? ys[r] : xs[r];
      sq2[q] = rc[q].x * rc[q].x + rc[q].y * rc[q].y;
      acc[q] = 0.f;
    }
    if (half == 0) {
#pragma unroll 4
      for (int t = 0; t < 64; ++t) {
        const int j = (t << 6) + lane;
        const float2 c = yk[j]; const float w = P[j];
#pragma unroll
        for (int q = 0; q < 8; ++q)
          acc[q] += exp2f(fmaf(c.x, rc[q].x, fmaf(c.y, rc[q].y, w)));
      }
    } else {
#pragma unroll 4
      for (int t = 0; t < 64; ++t) {
        const int i = (t << 6) + lane;
        const float2 c = xk[i]; const float w = P[i];
#pragma unroll
        for (int q = 0; q < 8; ++q)
          acc[q] += exp2f(fmaf(c.x, rc[q].x, fmaf(c.y, rc[q].y, w)));
      }
    }
#pragma unroll
    for (int q = 0; q < 8; ++q) acc[q] = wsum(acc[q]);
    if (lane == 0) {
#pragma unroll
      for (int q = 0; q < 8; ++q) {
        const int r = base + q;
        const float val = F_EPS * fmaf(LN2, log2f(acc[q]), -5.f * sq2[q]) - F_EPSLOGZ;
        astore(half ? &gcg[r] : &fcg[r], val);
      }
    }
  }
  tgt++; gbar(sync, berr, sred, &sdone, bid, tid, lane, wib, tgt, 0, ywn);

  // ==== phase P: plan partial sums (16 rows/block) ====
  {
    {
      float tmp[16];
#pragma unroll
      for (int q = 0; q < 16; ++q) tmp[q] = aload(&gcg[tid + (q << 8)]);
#pragma unroll
      for (int q = 0; q < 16; ++q) {
        const int k = tid + (q << 8);
        const float2 yp = ys[k];
        const float y2k = yp.x * yp.x + yp.y * yp.y;
        P[k] = fmaf(-HK2, y2k, fmaf(-K2, tmp[q], log2f(yw[k]))) - C1;
      }
    }
    __syncthreads();
    float a[4], wx[4];
#pragma unroll
    for (int q = 0; q < 4; ++q) {
      const int r = c0 + q;
      const float x2r = xr[q].x * xr[q].x + xr[q].y * xr[q].y;
      wx[q] = fmaf(-HK2, x2r, fmaf(-K2, aload(&fcg[r]), l2xw[q]));
      a[q] = 0.f;
    }
#pragma unroll 8
    for (int t = 0; t < 64; ++t) {
      const int j = (t << 6) + lane;
      const float2 c = yk[j]; const float w = P[j];
#pragma unroll
      for (int q = 0; q < 4; ++q)
        a[q] += exp2f(fmaf(c.x, xr[q].x, fmaf(c.y, xr[q].y, w)));
    }
#pragma unroll
    for (int q = 0; q < 4; ++q) a[q] = wsum(a[q]);
    if (lane == 0)
      ew[wib] = ((exp2f(wx[0]) * a[0] + exp2f(wx[1]) * a[1]) +
                 (exp2f(wx[2]) * a[2] + exp2f(wx[3]) * a[3]));
    __syncthreads();
    if (tid == 0) astore(&part[bid], (ew[0] + ew[1]) + (ew[2] + ew[3]));
  }
  tgt++; gbar(sync, berr, sred, &sdone, bid, tid, lane, wib, tgt, 0, ywn);

  // ==== final: block 0 reduces everything ====
  if (bid == 0) {
    float a1 = 0.f, a2 = 0.f;
    for (int i = tid; i < N; i += BT) {
      a1 += aload(&fcg[i]) * xw[i];
      a2 += aload(&gcg[i]) * yw[i];
    }
    const float a3 = aload(&part[tid]);   // NB == BT
    float* r1 = P; float* r2 = P + 256; float* r3 = P + 512;
    r1[tid] = a1; r2[tid] = a2; r3[tid] = a3; __syncthreads();
    for (int s2 = 128; s2; s2 >>= 1) {
      if (tid < s2) { r1[tid] += r1[tid + s2]; r2[tid] += r2[tid + s2]; r3[tid] += r3[tid + s2]; }
      __syncthreads();
    }
    if (tid == 0) out[0] = -r1[0] - r2[0] - F_EPS * r3[0];
  }
}

extern "C" void kernel_launch(void* const* d_in, const int* in_sizes, int n_in,
                              void* d_out, int out_size, void* d_ws, size_t ws_size,
                              hipStream_t stream) {
  const float*  xw  = (const float*)d_in[0];
  const float2* xs2 = (const float2*)d_in[1];
  const float*  yw  = (const float*)d_in[2];
  const float2* ys2 = (const float2*)d_in[3];
  float* out = (float*)d_out;

  float* w = (float*)d_ws;
  float *pcol = w,          *prow = w + 4096,  *psav = w + 8192,
        *fcg  = w + 12288,  *gcg  = w + 16384,
        *berr = w + 20480,  *part = w + 20736;
  unsigned* sync = (unsigned*)(w + 20992);   // 1280 uints: arrive[256]x4 | flag[16]x16

  fused_kernel<<<NB, BT, 0, stream>>>(xw, xs2, yw, ys2,
                                      pcol, prow, psav, berr, fcg, gcg, part, out, sync);
}